// Round 4
// baseline (27245.880 us; speedup 1.0000x reference)
//
#include <hip/hip_runtime.h>
#include <math.h>

#define KDIM 2560
#define DDIM 512
#define NB 64

#define QM 2560
#define QN 512
#define PW 16
#define QTH 512
#define QRW 5
#define UW 10

// out layout (floats): m_cor @0 (2560), l_cor @2560 (2560*2560), u @6556160 (512),
// error @6556672 (512), diffusion @6557184 (1)
#define OUT_LCOR 2560
#define OUT_U    6556160
#define OUT_ERR  6556672
#define OUT_DIFF 6557184

// scal layout (doubles): [0..4]=p_pat, [5..9]=pinv_pat, [10]=diffusion

__global__ void k_setup(const float* dt, double* scal){
  if (threadIdx.x==0 && blockIdx.x==0){
    double adt = fabs((double)dt[0]);
    const double scales[5] = {24.0,6.0,2.0,1.0,1.0};
    for (int i=0;i<5;i++){
      double pw = (double)(4-i)+0.5;
      scal[i]   = pow(adt, pw)/scales[i];
      scal[5+i] = pow(adt,-pw)*scales[i];
    }
  }
}

__global__ void k_mext(const float* a, const float* m0, const double* scal, double* mext){
  int r = blockIdx.x*blockDim.x + threadIdx.x;
  if (r>=KDIM) return;
  int j=r/5, i=r%5;
  const float* arow = a + (size_t)r*KDIM + 5*j;
  const float* m0b  = m0 + 5*j;
  double acc=0;
  for (int l=0;l<5;l++) acc += (double)arow[l]*scal[5+l]*(double)m0b[l];
  mext[r] = scal[i]*acc;
}

__global__ void k_mobs(const float* H, const float* bias, const double* mext, double* mobs){
  __shared__ double red[256];
  int r = blockIdx.x;
  const float* Hr = H + (size_t)r*KDIM;
  double acc=0;
  for (int c=threadIdx.x;c<KDIM;c+=256) acc += (double)Hr[c]*mext[c];
  red[threadIdx.x]=acc; __syncthreads();
  for (int s=128;s>0;s>>=1){ if (threadIdx.x<s) red[threadIdx.x]+=red[threadIdx.x+s]; __syncthreads(); }
  if (threadIdx.x==0) mobs[r] = red[0] - (double)bias[r];
}

// A (col-major QM x QN) = (H @ (p_inv[:,None]*q)).T in fp64
__global__ void k_A(const float* H, const float* q, const double* scal, double* A){
  int idx = blockIdx.x*blockDim.x+threadIdx.x;
  if (idx >= QN*QM) return;
  int j = idx / QM;
  int i = idx % QM;
  int bi = i/5;
  double acc=0;
  for (int t=0;t<5;t++)
    acc += (double)H[(size_t)j*QM + 5*bi+t]*scal[5+t]*(double)q[(size_t)(5*bi+t)*QM + i];
  A[idx] = acc;
}

// ---- Householder QR: register-resident panel + fused VtV/T build ----
__global__ __launch_bounds__(QTH) void qr_panel(double* A, double* beta, double* vhead,
                                                int col0, double* Tbuf){
  __shared__ double red[8][PW];
  __shared__ double rednorm[8];
  __shared__ double wsh[PW];
  __shared__ double sh[4];          // 0: x1, 1: v1, 2: b
  __shared__ double alphas[PW], betas[PW];
  __shared__ double VtV[PW*PW];
  __shared__ double Tsh[PW][PW];
  int tid=threadIdx.x, wid=tid>>6, lane=tid&63;
  int m = QM - col0;
  double x[QRW][PW];
  #pragma unroll
  for (int w=0;w<QRW;w++){
    int lr = tid + w*QTH;
    #pragma unroll
    for (int j=0;j<PW;j++)
      x[w][j] = (lr<m)? A[(size_t)(col0+j)*QM + col0+lr] : 0.0;
  }
  for (int j=0;j<PW;j++){
    double ps=0;
    #pragma unroll
    for (int w=0;w<QRW;w++){
      int lr=tid+w*QTH;
      if (lr>=j && lr<m) ps += x[w][j]*x[w][j];
    }
    #pragma unroll
    for (int o=32;o>0;o>>=1) ps += __shfl_down(ps,o);
    if (lane==0) rednorm[wid]=ps;
    if (tid==j) sh[0]=x[0][j];
    __syncthreads();
    if (tid==0){
      double s0=0;
      for (int t=0;t<8;t++) s0+=rednorm[t];
      double x1=sh[0];
      double nrm=sqrt(s0);
      double alpha=(x1>=0.0)?-nrm:nrm;     // LAPACK sign
      double v1=x1-alpha;
      double vtv=s0-2.0*alpha*x1+alpha*alpha;
      double b=(vtv>0.0)?2.0/vtv:0.0;
      sh[1]=v1; sh[2]=b;
      alphas[j]=alpha; betas[j]=b;
      beta[col0+j]=b; vhead[col0+j]=v1;
    }
    __syncthreads();
    if (tid==j) x[0][j]=sh[1];
    double b=sh[2];
    double acc[PW];
    #pragma unroll
    for (int t=0;t<PW;t++) acc[t]=0;
    #pragma unroll
    for (int w=0;w<QRW;w++){
      int lr=tid+w*QTH;
      bool on=(lr>=j && lr<m);
      double v = on? x[w][j]:0.0;
      #pragma unroll
      for (int t=0;t<PW;t++)
        if (t>j) acc[t]+=v*x[w][t];
    }
    #pragma unroll
    for (int t=0;t<PW;t++){
      double d=acc[t];
      #pragma unroll
      for (int o=32;o>0;o>>=1) d+=__shfl_down(d,o);
      if (lane==0) red[wid][t]=d;
    }
    __syncthreads();
    if (tid<PW){
      double tot=0;
      for (int t2=0;t2<8;t2++) tot+=red[t2][tid];
      wsh[tid]=b*tot;
    }
    __syncthreads();
    #pragma unroll
    for (int w=0;w<QRW;w++){
      int lr=tid+w*QTH;
      bool on=(lr>=j && lr<m);
      double v = on? x[w][j]:0.0;
      #pragma unroll
      for (int t=0;t<PW;t++)
        if (t>j) x[w][t]-=wsh[t]*v;
    }
  }
  // VtV (pairs i<j), 8 groups of 15
  for (int g=0;g<8;g++){
    double pp[15];
    #pragma unroll
    for (int t=0;t<15;t++) pp[t]=0;
    #pragma unroll
    for (int t=0;t<15;t++){
      int p=g*15+t;
      int jj=(int)((1.0+sqrt(1.0+8.0*(double)p))*0.5);
      if (jj*(jj-1)/2>p) jj--;
      int ii=p-jj*(jj-1)/2;
      #pragma unroll
      for (int w=0;w<QRW;w++){
        int lr=tid+w*QTH;
        if (lr>=jj && lr<m) pp[t]+=x[w][ii]*x[w][jj];
      }
    }
    #pragma unroll
    for (int t=0;t<15;t++){
      double d=pp[t];
      #pragma unroll
      for (int o=32;o>0;o>>=1) d+=__shfl_down(d,o);
      if (lane==0) red[wid][t]=d;
    }
    __syncthreads();
    if (tid<15){
      double tot=0;
      for (int t2=0;t2<8;t2++) tot+=red[t2][tid];
      int p=g*15+tid;
      int jj=(int)((1.0+sqrt(1.0+8.0*(double)p))*0.5);
      if (jj*(jj-1)/2>p) jj--;
      int ii=p-jj*(jj-1)/2;
      VtV[ii*PW+jj]=tot;
    }
    __syncthreads();
  }
  if (tid<PW){
    int i=tid;
    Tsh[i][i]=betas[i];
    for (int j2=i+1;j2<PW;j2++){
      double z=0;
      for (int t=i;t<j2;t++) z+=Tsh[i][t]*VtV[t*PW+j2];
      Tsh[i][j2]=-betas[j2]*z;
    }
    for (int j2=0;j2<i;j2++) Tsh[i][j2]=0.0;
  }
  __syncthreads();
  for (int e=tid;e<PW*PW;e+=QTH) Tbuf[e]=Tsh[e/PW][e&15];
  #pragma unroll
  for (int w=0;w<QRW;w++){
    int lr=tid+w*QTH;
    if (lr<m){
      #pragma unroll
      for (int j=0;j<PW;j++)
        A[(size_t)(col0+j)*QM+col0+lr] = (lr==j)? alphas[j] : x[w][j];
    }
  }
}

// fused trailing update: a_cc -= V * (T^T (V^T a_cc)); one block per trailing column
__global__ __launch_bounds__(256) void qr_update(double* A, const double* vhead,
                                                 const double* Tbuf, int col0){
  __shared__ double redu[4][PW];
  __shared__ double ysh[PW];
  __shared__ double wsh[PW];
  int tid=threadIdx.x, wid=tid>>6, lane=tid&63;
  int cc=col0+PW+blockIdx.x;
  int m=QM-col0;
  double a[UW];
  #pragma unroll
  for (int w=0;w<UW;w++){
    int lr=tid+w*256;
    a[w]=(lr<m)? A[(size_t)cc*QM+col0+lr] : 0.0;
  }
  double acc[PW];
  #pragma unroll
  for (int j=0;j<PW;j++) acc[j]=0;
  #pragma unroll
  for (int w=0;w<UW;w++){
    int lr=tid+w*256;
    if (lr<m){
      #pragma unroll
      for (int j=0;j<PW;j++){
        double vj;
        if (lr>j)       vj=A[(size_t)(col0+j)*QM+col0+lr];
        else if (lr==j) vj=vhead[col0+j];
        else            vj=0.0;
        acc[j]+=vj*a[w];
      }
    }
  }
  #pragma unroll
  for (int j=0;j<PW;j++){
    double d=acc[j];
    #pragma unroll
    for (int o=32;o>0;o>>=1) d+=__shfl_down(d,o);
    if (lane==0) redu[wid][j]=d;
  }
  __syncthreads();
  if (tid<PW){
    double y=0;
    #pragma unroll
    for (int t=0;t<4;t++) y+=redu[t][tid];
    ysh[tid]=y;
  }
  __syncthreads();
  if (tid<PW){
    double s=0;
    for (int t=0;t<=tid;t++) s+=Tbuf[t*PW+tid]*ysh[t];
    wsh[tid]=s;
  }
  __syncthreads();
  #pragma unroll
  for (int w=0;w<UW;w++){
    int lr=tid+w*256;
    if (lr<m){
      double s=0;
      #pragma unroll
      for (int j=0;j<PW;j++){
        double vj;
        if (lr>j)       vj=A[(size_t)(col0+j)*QM+col0+lr];
        else if (lr==j) vj=vhead[col0+j];
        else            vj=0.0;
        s+=vj*wsh[j];
      }
      A[(size_t)cc*QM+col0+lr]=a[w]-s;
    }
  }
}

__global__ void k_extractR(const double* A, double* Rq){
  int idx = blockIdx.x*blockDim.x+threadIdx.x;
  if (idx >= QN*QN) return;
  int r = idx/QN, c = idx%QN;
  Rq[idx] = (r<=c) ? A[(size_t)c*QM + r] : 0.0;
}

__global__ void k_colnorm(const double* Rq, double* g1d){
  int c = blockIdx.x*blockDim.x+threadIdx.x;
  if (c>=QN) return;
  double s=0;
  for (int r=0;r<=c;r++){ double v=Rq[(size_t)r*QN+c]; s+=v*v; }
  g1d[c]=s;
}

// panel-blocked backward solve R x = m_obs; diffusion + error
__global__ __launch_bounds__(512) void k_resw(const double* Rq, const double* mobs, const double* g1d,
                                              double* scal, float* out){
  __shared__ double b[DDIM];
  __shared__ double xs[DDIM];
  __shared__ double D[NB][NB+1];
  __shared__ double red[DDIM];
  int tid=threadIdx.x;
  b[tid]=mobs[tid];
  __syncthreads();
  for (int p=7;p>=0;p--){
    int b0=p*NB;
    for (int e=tid;e<NB*NB;e+=512){int i=e>>6,j2=e&63; D[i][j2]=Rq[(size_t)(b0+i)*DDIM+b0+j2];}
    __syncthreads();
    if (tid<64){
      double bi=b[b0+tid];
      for (int k=NB-1;k>=0;k--){
        double bk=__shfl(bi,k);
        double xk=bk/D[k][k];
        if (tid<k) bi-=D[tid][k]*xk;
        if (tid==k) bi=xk;
      }
      xs[b0+tid]=bi;
    }
    __syncthreads();
    if (tid<b0){
      double s=0;
      #pragma unroll 8
      for (int j2=0;j2<NB;j2++) s+=Rq[(size_t)tid*DDIM+b0+j2]*xs[b0+j2];
      b[tid]-=s;
    }
    __syncthreads();
  }
  red[tid]=xs[tid]*xs[tid]; __syncthreads();
  for (int s=256;s>0;s>>=1){ if (tid<s) red[tid]+=red[tid+s]; __syncthreads(); }
  double diff=sqrt(red[0]/(double)DDIM);
  if (tid==0){ scal[10]=diff; out[OUT_DIFF]=(float)diff; }
  out[OUT_ERR+tid]=(float)(diff*sqrt(fmax(g1d[tid],0.0)));
}

// X = a @ (p_inv[:,None]*l0)
__global__ void k_X(const float* a, const float* l0, const double* scal, float* X){
  int idx=blockIdx.x*blockDim.x+threadIdx.x;
  if (idx>=KDIM*KDIM) return;
  int r=idx/KDIM, c=idx%KDIM;
  int j=r/5;
  const float* arow = a + (size_t)r*KDIM + 5*j;
  double acc=0;
  for (int l=0;l<5;l++)
    acc += (double)arow[l]*scal[5+l]*(double)l0[(size_t)(5*j+l)*KDIM+c];
  X[idx]=(float)acc;
}

// ---- 64x64-tile GEMM, 4x4 per thread, fp64 accumulate ----
// A: ATR? (K x M row-major) : (M x K row-major). B: BTR? (N x K) : (K x N).
// MODE 0: double C = acc; 1: double C -= acc; 2: float C = acc.
// kmode 0: [0,K); 1: ks=n0; 2: ke=min(K,n0+64)
template<typename TA,int ATR,typename TB,int BTR,int MODE>
__global__ __launch_bounds__(256) void gemm64(const TA* __restrict__ A,int lda,
                                              const TB* __restrict__ B,int ldb,
                                              void* __restrict__ Cv,int ldc,
                                              int K,int kmode){
  __shared__ double As[16][65];
  __shared__ double Bs[16][65];
  int tid=threadIdx.x, tx=tid&15, ty=tid>>4;
  int n0=blockIdx.x*64, m0=blockIdx.y*64;
  int ks=0, ke=K;
  if (kmode==1) ks=n0;
  else if (kmode==2) ke=min(K,n0+64);
  double acc[4][4]={};
  for (int k0=ks;k0<ke;k0+=16){
    if (ATR){
      for (int e=tid;e<16*64;e+=256){int k=e>>6,mm=e&63; As[k][mm]=(double)A[(size_t)(k0+k)*lda+m0+mm];}
    } else {
      for (int e=tid;e<64*16;e+=256){int mm=e>>4,k=e&15; As[k][mm]=(double)A[(size_t)(m0+mm)*lda+k0+k];}
    }
    if (BTR){
      for (int e=tid;e<64*16;e+=256){int nn=e>>4,k=e&15; Bs[k][nn]=(double)B[(size_t)(n0+nn)*ldb+k0+k];}
    } else {
      for (int e=tid;e<16*64;e+=256){int k=e>>6,nn=e&63; Bs[k][nn]=(double)B[(size_t)(k0+k)*ldb+n0+nn];}
    }
    __syncthreads();
    #pragma unroll
    for (int t=0;t<16;t++){
      double av[4],bv[4];
      #pragma unroll
      for (int i=0;i<4;i++){av[i]=As[t][ty+16*i];bv[i]=Bs[t][tx+16*i];}
      #pragma unroll
      for (int i=0;i<4;i++)
        #pragma unroll
        for (int j=0;j<4;j++) acc[i][j]+=av[i]*bv[j];
    }
    __syncthreads();
  }
  #pragma unroll
  for (int i=0;i<4;i++){
    #pragma unroll
    for (int j=0;j<4;j++){
      size_t idx=(size_t)(m0+ty+16*i)*ldc+n0+tx+16*j;
      if (MODE==0) ((double*)Cv)[idx]=acc[i][j];
      else if (MODE==1) ((double*)Cv)[idx]-=acc[i][j];
      else ((float*)Cv)[idx]=(float)acc[i][j];
    }
  }
}

// G (lower tiles) = X X^T, exploiting X[r,c]=0 for c >= 5*(r/5)+5
__global__ __launch_bounds__(256) void syrk_lower(const float* __restrict__ X, double* __restrict__ G, int n){
  int S0=blockIdx.x*64, R0=blockIdx.y*64;
  if (S0>R0) return;
  __shared__ double As[16][65];
  __shared__ double Bs[16][65];
  int tid=threadIdx.x, tx=tid&15, ty=tid>>4;
  int kend=min(n, S0+80);
  double acc[4][4]={};
  for (int k0=0;k0<kend;k0+=16){
    for (int e=tid;e<64*16;e+=256){int mm=e>>4,k=e&15; As[k][mm]=(double)X[(size_t)(R0+mm)*n+k0+k];}
    for (int e=tid;e<64*16;e+=256){int nn=e>>4,k=e&15; Bs[k][nn]=(double)X[(size_t)(S0+nn)*n+k0+k];}
    __syncthreads();
    #pragma unroll
    for (int t=0;t<16;t++){
      double av[4],bv[4];
      #pragma unroll
      for (int i=0;i<4;i++){av[i]=As[t][ty+16*i];bv[i]=Bs[t][tx+16*i];}
      #pragma unroll
      for (int i=0;i<4;i++)
        #pragma unroll
        for (int j=0;j<4;j++) acc[i][j]+=av[i]*bv[j];
    }
    __syncthreads();
  }
  #pragma unroll
  for (int i=0;i<4;i++)
    #pragma unroll
    for (int j=0;j<4;j++)
      G[(size_t)(R0+ty+16*i)*n+S0+tx+16*j]=acc[i][j];
}

__global__ void k_addqqt(const float* q, const double* scal, double* G2){
  int idx=blockIdx.x*blockDim.x+threadIdx.x;
  if (idx>=DDIM*15) return;
  int j=idx/15, t=idx%15;
  int i=0; while (t >= i+1){ t-=i+1; i++; }
  int jj=t;
  double acc=0;
  for (int k=0;k<5;k++) acc += (double)q[(size_t)i*KDIM+k]*(double)q[(size_t)jj*KDIM+k];
  double dd=scal[10]*scal[10];
  G2[(size_t)(5*j+i)*KDIM + 5*j+jj] += dd*acc;
}

// ---- blocked Cholesky ----
__global__ __launch_bounds__(256) void chol_diag(double* A, int n, int k0){
  __shared__ double P[NB][NB+1];
  int tid=threadIdx.x;
  for (int e=tid;e<NB*NB;e+=256){int r=e>>6,c=e&63;P[r][c]=A[(size_t)(k0+r)*n+k0+c];}
  int tx=tid&15, ty=tid>>4;
  __syncthreads();
  for (int j=0;j<NB;j++){
    double pj=P[j][j];
    __syncthreads();
    double rpj=1.0/sqrt(fmax(pj,1e-280));
    if (tid>j && tid<NB) P[tid][j]*=rpj;
    if (tid==j) P[j][j]=sqrt(fmax(pj,1e-280));
    __syncthreads();
    #pragma unroll
    for (int a2=0;a2<4;a2++){
      int r=ty+16*a2;
      double lrj=P[r][j];
      #pragma unroll
      for (int b2=0;b2<4;b2++){
        int c=tx+16*b2;
        if (r>j && c>j && c<=r) P[r][c]-=lrj*P[c][j];
      }
    }
    __syncthreads();
  }
  for (int e=tid;e<NB*NB;e+=256){int r=e>>6,c=e&63;A[(size_t)(k0+r)*n+k0+c]=P[r][c];}
}

// rows below panel: Ar = Ar * Lbb^{-T}; LDS-staged coalesced loads, register solve
__global__ __launch_bounds__(256) void chol_trsm(double* A,int n,int k0){
  __shared__ double Ls[NB][NB+1];
  __shared__ double St[NB][NB+1];
  __shared__ double rec[NB];
  int tid=threadIdx.x;
  for (int e=tid;e<NB*NB;e+=256){int r=e>>6,c=e&63;Ls[r][c]=A[(size_t)(k0+r)*n+k0+c];}
  __syncthreads();
  if (tid<NB) rec[tid]=1.0/Ls[tid][tid];
  int base=k0+NB+blockIdx.x*256;
  int myrow=base+tid;
  int mychunk=tid>>6, lrow=tid&63;
  double ar[NB];
  for (int ch=0;ch<4;ch++){
    int r0=base+ch*64;
    for (int e=tid;e<NB*NB;e+=256){
      int r=e>>6,c=e&63;
      if (r0+r<n) St[r][c]=A[(size_t)(r0+r)*n+k0+c];
    }
    __syncthreads();
    if (mychunk==ch && myrow<n){
      #pragma unroll
      for (int c=0;c<NB;c++) ar[c]=St[lrow][c];
    }
    __syncthreads();
  }
  if (myrow<n){
    #pragma unroll
    for (int j=0;j<NB;j++){
      double s=ar[j];
      #pragma unroll
      for (int t=0;t<j;t++) s-=ar[t]*Ls[j][t];
      ar[j]=s*rec[j];
    }
  }
  for (int ch=0;ch<4;ch++){
    int r0=base+ch*64;
    if (mychunk==ch && myrow<n){
      #pragma unroll
      for (int c=0;c<NB;c++) St[lrow][c]=ar[c];
    }
    __syncthreads();
    for (int e=tid;e<NB*NB;e+=256){
      int r=e>>6,c=e&63;
      if (r0+r<n) A[(size_t)(r0+r)*n+k0+c]=St[r][c];
    }
    __syncthreads();
  }
}

// trailing syrk update: A_trail -= P P^T (64-wide K), 64x64 tiles, skip upper
__global__ __launch_bounds__(256) void chol_syrk(double* A,int n,int k0){
  int ts0=k0+NB;
  int S0=ts0+blockIdx.x*64, R0=ts0+blockIdx.y*64;
  if (S0>R0) return;
  __shared__ double As[16][65];
  __shared__ double Bs[16][65];
  int tid=threadIdx.x, tx=tid&15, ty=tid>>4;
  double acc[4][4]={};
  for (int k0i=0;k0i<NB;k0i+=16){
    for (int e=tid;e<64*16;e+=256){int mm=e>>4,k=e&15; As[k][mm]=A[(size_t)(R0+mm)*n+k0+k0i+k];}
    for (int e=tid;e<64*16;e+=256){int nn=e>>4,k=e&15; Bs[k][nn]=A[(size_t)(S0+nn)*n+k0+k0i+k];}
    __syncthreads();
    #pragma unroll
    for (int t=0;t<16;t++){
      double av[4],bv[4];
      #pragma unroll
      for (int i=0;i<4;i++){av[i]=As[t][ty+16*i];bv[i]=Bs[t][tx+16*i];}
      #pragma unroll
      for (int i=0;i<4;i++)
        #pragma unroll
        for (int j=0;j<4;j++) acc[i][j]+=av[i]*bv[j];
    }
    __syncthreads();
  }
  #pragma unroll
  for (int i=0;i<4;i++)
    #pragma unroll
    for (int j=0;j<4;j++)
      A[(size_t)(R0+ty+16*i)*n+S0+tx+16*j]-=acc[i][j];
}

static void chol_blocked(double* A, int n, hipStream_t stream){
  for (int k0=0;k0<n;k0+=NB){
    chol_diag<<<1,256,0,stream>>>(A,n,k0);
    int m = n-k0-NB;
    if (m>0){
      chol_trsm<<<(m+255)/256,256,0,stream>>>(A,n,k0);
      chol_syrk<<<dim3(m/64,m/64),256,0,stream>>>(A,n,k0);
    }
  }
}

// l_ext (f32) = p[:,None] * chol(G2), zero strict upper
__global__ void k_extract(const double* G2, const double* scal, float* lext){
  int idx=blockIdx.x*blockDim.x+threadIdx.x;
  if (idx>=KDIM*KDIM) return;
  int r=idx/KDIM, c=idx%KDIM;
  double v = (c<=r)? scal[r%5]*G2[idx] : 0.0;
  lext[idx]=(float)v;
}

// ---- multi-RHS blocked triangular solves on Z (DDIM x KDIM) ----
__global__ __launch_bounds__(256) void trsm_fwd(const double* __restrict__ L,int n,int b0,
                                                double* __restrict__ Z,int ldz){
  __shared__ double Ls[NB][NB+1];
  __shared__ double rec[NB];
  int lin=threadIdx.x;
  for (int e=lin;e<NB*NB;e+=256){int r=e>>6,c=e&63;Ls[r][c]=L[(size_t)(b0+r)*n+b0+c];}
  __syncthreads();
  if (lin<NB) rec[lin]=1.0/Ls[lin][lin];
  __syncthreads();
  int col=blockIdx.x*256+lin;
  double z[NB];
  #pragma unroll
  for (int r=0;r<NB;r++) z[r]=Z[(size_t)(b0+r)*ldz+col];
  #pragma unroll
  for (int r=0;r<NB;r++){
    double s=z[r];
    #pragma unroll
    for (int t=0;t<r;t++) s-=Ls[r][t]*z[t];
    z[r]=s*rec[r];
  }
  #pragma unroll
  for (int r=0;r<NB;r++) Z[(size_t)(b0+r)*ldz+col]=z[r];
}

__global__ __launch_bounds__(256) void trsm_bwd(const double* __restrict__ L,int n,int b0,
                                                double* __restrict__ Z,int ldz){
  __shared__ double Ls[NB][NB+1];
  __shared__ double rec[NB];
  int lin=threadIdx.x;
  for (int e=lin;e<NB*NB;e+=256){int r=e>>6,c=e&63;Ls[r][c]=L[(size_t)(b0+r)*n+b0+c];}
  __syncthreads();
  if (lin<NB) rec[lin]=1.0/Ls[lin][lin];
  __syncthreads();
  int col=blockIdx.x*256+lin;
  double z[NB];
  #pragma unroll
  for (int r=0;r<NB;r++) z[r]=Z[(size_t)(b0+r)*ldz+col];
  #pragma unroll
  for (int ri=NB-1;ri>=0;ri--){
    double s=z[ri];
    #pragma unroll
    for (int t=ri+1;t<NB;t++) s-=Ls[t][ri]*z[t];
    z[ri]=s*rec[ri];
  }
  #pragma unroll
  for (int r=0;r<NB;r++) Z[(size_t)(b0+r)*ldz+col]=z[r];
}

// m_cor = m_ext - Z^T @ m_obs; also u
__global__ void k_mcor(const double* Z, const double* mobs, const double* mext, float* out){
  __shared__ double mo[DDIM];
  for (int s=threadIdx.x;s<DDIM;s+=256) mo[s]=mobs[s];
  __syncthreads();
  int r=blockIdx.x*256+threadIdx.x;
  if (r>=KDIM) return;
  double acc=0;
  for (int s=0;s<DDIM;s++) acc += Z[(size_t)s*KDIM+r]*mo[s];
  double mc = mext[r]-acc;
  out[r]=(float)mc;
  if (r%5==0) out[OUT_U + r/5]=(float)mc;
}

// l_cor = l_ext - Z^T @ l_obs_ns (64x64 tiles)
__global__ __launch_bounds__(256) void k_lcor(const double* __restrict__ Z, const float* __restrict__ lobs,
                                              const float* __restrict__ lext, float* __restrict__ out){
  __shared__ double As[16][65];
  __shared__ double Bs[16][65];
  int tid=threadIdx.x, tx=tid&15, ty=tid>>4;
  int n0=blockIdx.x*64, m0=blockIdx.y*64;
  double acc[4][4]={};
  for (int k0=0;k0<DDIM;k0+=16){
    for (int e=tid;e<16*64;e+=256){int k=e>>6,mm=e&63; As[k][mm]=Z[(size_t)(k0+k)*KDIM+m0+mm];}
    for (int e=tid;e<16*64;e+=256){int k=e>>6,nn=e&63; Bs[k][nn]=(double)lobs[(size_t)(k0+k)*KDIM+n0+nn];}
    __syncthreads();
    #pragma unroll
    for (int t=0;t<16;t++){
      double av[4],bv[4];
      #pragma unroll
      for (int i=0;i<4;i++){av[i]=As[t][ty+16*i];bv[i]=Bs[t][tx+16*i];}
      #pragma unroll
      for (int i=0;i<4;i++)
        #pragma unroll
        for (int j=0;j<4;j++) acc[i][j]+=av[i]*bv[j];
    }
    __syncthreads();
  }
  #pragma unroll
  for (int i=0;i<4;i++)
    #pragma unroll
    for (int j=0;j<4;j++){
      size_t idx=(size_t)(m0+ty+16*i)*KDIM+n0+tx+16*j;
      out[OUT_LCOR+idx]=(float)((double)lext[idx]-acc[i][j]);
    }
}

extern "C" void kernel_launch(void* const* d_in, const int* in_sizes, int n_in,
                              void* d_out, int out_size, void* d_ws, size_t ws_size,
                              hipStream_t stream) {
  const float* m0  = (const float*)d_in[0];
  const float* l0  = (const float*)d_in[1];
  const float* H   = (const float*)d_in[2];
  const float* bias= (const float*)d_in[3];
  const float* dt  = (const float*)d_in[4];
  const float* a   = (const float*)d_in[5];
  const float* q   = (const float*)d_in[6];
  float* out = (float*)d_out;

  char* w=(char*)d_ws;
  auto alloc=[&](size_t bytes)->char*{ char* p=w; w += ((bytes+255)/256)*256; return p; };
  double* scal =(double*)alloc(16*8);
  double* mext =(double*)alloc((size_t)KDIM*8);
  double* mobs =(double*)alloc((size_t)DDIM*8);
  double* g1d  =(double*)alloc((size_t)DDIM*8);
  double* betaA=(double*)alloc((size_t)QN*8);
  double* vheadA=(double*)alloc((size_t)QN*8);
  double* Tbuf =(double*)alloc((size_t)PW*PW*8);
  double* Aq   =(double*)alloc((size_t)QM*QN*8);     // QR working matrix (fp64)
  double* Rq   =(double*)alloc((size_t)QN*QN*8);     // R factor
  double* S    =(double*)alloc((size_t)DDIM*DDIM*8); // innovation Gram + chol
  double* G2   =(double*)alloc((size_t)KDIM*KDIM*8); // big Gram -> chol; reused as Z
  float*  LOBS =(float*) alloc((size_t)DDIM*KDIM*4);
  float*  X    =(float*) alloc((size_t)KDIM*KDIM*4); // X; later l_ext
  double* Z    = G2;       // fp64 DDIM x KDIM, alias after k_extract
  float*  LEXT = X;

  // ---- extrapolate mean, observe ----
  k_setup<<<1,1,0,stream>>>(dt, scal);
  k_mext<<<(KDIM+255)/256,256,0,stream>>>(a, m0, scal, mext);
  k_mobs<<<DDIM,256,0,stream>>>(H, bias, mext, mobs);

  // ---- first QR: Householder fp64, LAPACK signs ----
  k_A<<<(QN*QM+255)/256,256,0,stream>>>(H, q, scal, Aq);
  for (int p=0;p<QN/PW;p++){
    int col0=p*PW;
    qr_panel<<<1,QTH,0,stream>>>(Aq, betaA, vheadA, col0, Tbuf);
    int ntr = QN - col0 - PW;
    if (ntr>0) qr_update<<<ntr,256,0,stream>>>(Aq, vheadA, Tbuf, col0);
  }
  k_extractR<<<(QN*QN+255)/256,256,0,stream>>>(Aq, Rq);
  k_colnorm<<<(QN+255)/256,256,0,stream>>>(Rq, g1d);
  k_resw<<<1,512,0,stream>>>(Rq, mobs, g1d, scal, out);

  // ---- extrapolated covariance sqrt via Gram + Cholesky ----
  k_X<<<(KDIM*KDIM+255)/256,256,0,stream>>>(a, l0, scal, X);
  syrk_lower<<<dim3(KDIM/64,KDIM/64),256,0,stream>>>(X, G2, KDIM);
  k_addqqt<<<(DDIM*15+255)/256,256,0,stream>>>(q, scal, G2);
  chol_blocked(G2, KDIM, stream);
  k_extract<<<(KDIM*KDIM+255)/256,256,0,stream>>>(G2, scal, LEXT);  // G2 dead -> Z

  // ---- correction ----
  // LOBS = H @ LEXT (LEXT lower-triangular: k starts at n0)
  gemm64<float,0,float,0,2><<<dim3(KDIM/64,DDIM/64),256,0,stream>>>(H,KDIM, LEXT,KDIM, LOBS,KDIM, KDIM, 1);
  // S = LOBS @ LOBS^T
  gemm64<float,0,float,1,0><<<dim3(DDIM/64,DDIM/64),256,0,stream>>>(LOBS,KDIM, LOBS,KDIM, S,DDIM, KDIM, 0);
  chol_blocked(S, DDIM, stream);
  // Z = LOBS @ LEXT^T  (crosscov^T; LEXT rows n0..n0+63 nonzero only k<n0+64)
  gemm64<float,0,float,1,0><<<dim3(KDIM/64,DDIM/64),256,0,stream>>>(LOBS,KDIM, LEXT,KDIM, Z,KDIM, KDIM, 2);
  // cho_solve: Z <- L^{-1} Z ; Z <- L^{-T} Z  (then gain = Z^T)
  for (int b=0;b<DDIM;b+=NB){
    trsm_fwd<<<KDIM/256,256,0,stream>>>(S, DDIM, b, Z, KDIM);
    int m = DDIM-b-NB;
    if (m>0)
      gemm64<double,0,double,0,1><<<dim3(KDIM/64,m/64),256,0,stream>>>(
        S+(size_t)(b+NB)*DDIM+b, DDIM, Z+(size_t)b*KDIM, KDIM,
        Z+(size_t)(b+NB)*KDIM, KDIM, NB, 0);
  }
  for (int b=DDIM-NB;b>=0;b-=NB){
    trsm_bwd<<<KDIM/256,256,0,stream>>>(S, DDIM, b, Z, KDIM);
    if (b>0)
      gemm64<double,1,double,0,1><<<dim3(KDIM/64,b/64),256,0,stream>>>(
        S+(size_t)b*DDIM, DDIM, Z+(size_t)b*KDIM, KDIM,
        Z, KDIM, NB, 0);
  }

  k_mcor<<<(KDIM+255)/256,256,0,stream>>>(Z, mobs, mext, out);
  k_lcor<<<dim3(KDIM/64,KDIM/64),256,0,stream>>>(Z, LOBS, LEXT, out);
}

// Round 5
// 18185.738 us; speedup vs baseline: 1.4982x; 1.4982x over previous
//
#include <hip/hip_runtime.h>
#include <math.h>

#define KDIM 2560
#define DDIM 512
#define NB 64

#define QM 2560
#define QN 512
#define PW 16
#define UW 10

// out layout (floats): m_cor @0 (2560), l_cor @2560 (2560*2560), u @6556160 (512),
// error @6556672 (512), diffusion @6557184 (1)
#define OUT_LCOR 2560
#define OUT_U    6556160
#define OUT_ERR  6556672
#define OUT_DIFF 6557184

// scal layout (doubles): [0..4]=p_pat, [5..9]=pinv_pat, [10]=diffusion

__global__ void k_setup(const float* dt, double* scal){
  if (threadIdx.x==0 && blockIdx.x==0){
    double adt = fabs((double)dt[0]);
    const double scales[5] = {24.0,6.0,2.0,1.0,1.0};
    for (int i=0;i<5;i++){
      double pw = (double)(4-i)+0.5;
      scal[i]   = pow(adt, pw)/scales[i];
      scal[5+i] = pow(adt,-pw)*scales[i];
    }
  }
}

__global__ void k_mext(const float* a, const float* m0, const double* scal, double* mext){
  int r = blockIdx.x*blockDim.x + threadIdx.x;
  if (r>=KDIM) return;
  int j=r/5, i=r%5;
  const float* arow = a + (size_t)r*KDIM + 5*j;
  const float* m0b  = m0 + 5*j;
  double acc=0;
  for (int l=0;l<5;l++) acc += (double)arow[l]*scal[5+l]*(double)m0b[l];
  mext[r] = scal[i]*acc;
}

__global__ void k_mobs(const float* H, const float* bias, const double* mext, double* mobs){
  __shared__ double red[256];
  int r = blockIdx.x;
  const float* Hr = H + (size_t)r*KDIM;
  double acc=0;
  for (int c=threadIdx.x;c<KDIM;c+=256) acc += (double)Hr[c]*mext[c];
  red[threadIdx.x]=acc; __syncthreads();
  for (int s=128;s>0;s>>=1){ if (threadIdx.x<s) red[threadIdx.x]+=red[threadIdx.x+s]; __syncthreads(); }
  if (threadIdx.x==0) mobs[r] = red[0] - (double)bias[r];
}

// A (col-major QM x QN) = (H @ (p_inv[:,None]*q)).T in fp64
__global__ void k_A(const float* H, const float* q, const double* scal, double* A){
  int idx = blockIdx.x*blockDim.x+threadIdx.x;
  if (idx >= QN*QM) return;
  int j = idx / QM;
  int i = idx % QM;
  int bi = i/5;
  double acc=0;
  for (int t=0;t<5;t++)
    acc += (double)H[(size_t)j*QM + 5*bi+t]*scal[5+t]*(double)q[(size_t)(5*bi+t)*QM + i];
  A[idx] = acc;
}

// ---- Householder QR (LAPACK signs), LDS-resident column panel factorization ----
// (register-resident variant spilled: 80 dbl/thread on a single-block kernel ->
//  one CU's scratch pipe, +7ms. Keep LDS version.)
__global__ __launch_bounds__(1024) void qr_panel(double* A, double* beta, double* vhead, int col0){
  __shared__ double vbuf[QM];
  __shared__ double red[1024];
  __shared__ double sh[2];
  int tid = threadIdx.x;
  for (int j=0;j<PW;j++){
    int c = col0 + j;
    double acc = 0;
    for (int r = c + tid; r < QM; r += 1024){
      double v = A[(size_t)c*QM + r];
      vbuf[r-c] = v;
      acc += v*v;
    }
    red[tid] = acc; __syncthreads();
    for (int s=512; s>0; s>>=1){ if (tid<s) red[tid]+=red[tid+s]; __syncthreads(); }
    if (tid==0){
      double s0 = red[0];
      double x1 = vbuf[0];
      double nrm = sqrt(s0);
      double alpha = (x1 >= 0.0) ? -nrm : nrm;   // LAPACK: R_cc = -sign(x1)*||x||
      double v1 = x1 - alpha;
      double vtv = s0 - 2.0*alpha*x1 + alpha*alpha;
      double b = (vtv > 0.0) ? 2.0/vtv : 0.0;
      vbuf[0] = v1;
      sh[0] = b;
      A[(size_t)c*QM + c] = alpha;
      beta[c] = b;
      vhead[c] = v1;
    }
    __syncthreads();
    double b = sh[0];
    int wid = tid >> 6, lane = tid & 63;
    int jj = j + 1 + wid;
    if (jj < PW && b != 0.0){
      int cc = col0 + jj;
      double d = 0;
      for (int r = c + lane; r < QM; r += 64)
        d += vbuf[r-c]*A[(size_t)cc*QM + r];
      #pragma unroll
      for (int off=32; off>0; off>>=1) d += __shfl_down(d, off);
      d = __shfl(d, 0);
      double sc = b*d;
      for (int r = c + lane; r < QM; r += 64)
        A[(size_t)cc*QM + r] -= sc*vbuf[r-c];
    }
    __syncthreads();
  }
}

// V^T V pairs + compact-WY T build
__global__ __launch_bounds__(512) void qr_vtvT(const double* A, const double* beta, const double* vhead,
                                               int col0, double* Tbuf){
  __shared__ double VtV[PW][PW];
  __shared__ double T[PW][PW];
  int tid = threadIdx.x, wid = tid>>6, lane = tid&63;
  for (int p = wid; p < PW*(PW-1)/2; p += 8){
    int i=0,j=1,cnt=p;
    for (j=1;j<PW;j++){ if (cnt < j){ i = cnt; break; } cnt -= j; }
    int ci = col0+i, cj = col0+j;
    double d=0;
    for (int r = cj + lane; r < QM; r += 64){
      double vi = A[(size_t)ci*QM + r];
      double vj = (r==cj) ? vhead[cj] : A[(size_t)cj*QM + r];
      d += vi*vj;
    }
    #pragma unroll
    for (int off=32;off>0;off>>=1) d += __shfl_down(d,off);
    if (lane==0) VtV[i][j]=d;
  }
  __syncthreads();
  if (tid==0){
    for (int j=0;j<PW;j++){
      double bj = beta[col0+j];
      T[j][j] = bj;
      for (int i=0;i<j;i++){
        double z=0;
        for (int t=i;t<j;t++) z += T[i][t]*VtV[t][j];
        T[i][j] = -bj*z;
      }
    }
    for (int i=0;i<PW;i++) for (int j2=0;j2<PW;j2++)
      Tbuf[i*PW+j2] = (j2>=i)? T[i][j2] : 0.0;
  }
}

// fused trailing update: a_cc -= V * (T^T (V^T a_cc)); one block per trailing column
__global__ __launch_bounds__(256) void qr_update(double* A, const double* vhead,
                                                 const double* Tbuf, int col0){
  __shared__ double redu[4][PW];
  __shared__ double ysh[PW];
  __shared__ double wsh[PW];
  int tid=threadIdx.x, wid=tid>>6, lane=tid&63;
  int cc=col0+PW+blockIdx.x;
  int m=QM-col0;
  double a[UW];
  #pragma unroll
  for (int w=0;w<UW;w++){
    int lr=tid+w*256;
    a[w]=(lr<m)? A[(size_t)cc*QM+col0+lr] : 0.0;
  }
  double acc[PW];
  #pragma unroll
  for (int j=0;j<PW;j++) acc[j]=0;
  #pragma unroll
  for (int w=0;w<UW;w++){
    int lr=tid+w*256;
    if (lr<m){
      #pragma unroll
      for (int j=0;j<PW;j++){
        double vj;
        if (lr>j)       vj=A[(size_t)(col0+j)*QM+col0+lr];
        else if (lr==j) vj=vhead[col0+j];
        else            vj=0.0;
        acc[j]+=vj*a[w];
      }
    }
  }
  #pragma unroll
  for (int j=0;j<PW;j++){
    double d=acc[j];
    #pragma unroll
    for (int o=32;o>0;o>>=1) d+=__shfl_down(d,o);
    if (lane==0) redu[wid][j]=d;
  }
  __syncthreads();
  if (tid<PW){
    double y=0;
    #pragma unroll
    for (int t=0;t<4;t++) y+=redu[t][tid];
    ysh[tid]=y;
  }
  __syncthreads();
  if (tid<PW){
    double s=0;
    for (int t=0;t<=tid;t++) s+=Tbuf[t*PW+tid]*ysh[t];
    wsh[tid]=s;
  }
  __syncthreads();
  #pragma unroll
  for (int w=0;w<UW;w++){
    int lr=tid+w*256;
    if (lr<m){
      double s=0;
      #pragma unroll
      for (int j=0;j<PW;j++){
        double vj;
        if (lr>j)       vj=A[(size_t)(col0+j)*QM+col0+lr];
        else if (lr==j) vj=vhead[col0+j];
        else            vj=0.0;
        s+=vj*wsh[j];
      }
      A[(size_t)cc*QM+col0+lr]=a[w]-s;
    }
  }
}

__global__ void k_extractR(const double* A, double* Rq){
  int idx = blockIdx.x*blockDim.x+threadIdx.x;
  if (idx >= QN*QN) return;
  int r = idx/QN, c = idx%QN;
  Rq[idx] = (r<=c) ? A[(size_t)c*QM + r] : 0.0;
}

__global__ void k_colnorm(const double* Rq, double* g1d){
  int c = blockIdx.x*blockDim.x+threadIdx.x;
  if (c>=QN) return;
  double s=0;
  for (int r=0;r<=c;r++){ double v=Rq[(size_t)r*QN+c]; s+=v*v; }
  g1d[c]=s;
}

// panel-blocked backward solve R x = m_obs; diffusion + error
__global__ __launch_bounds__(512) void k_resw(const double* Rq, const double* mobs, const double* g1d,
                                              double* scal, float* out){
  __shared__ double b[DDIM];
  __shared__ double xs[DDIM];
  __shared__ double D[NB][NB+1];
  __shared__ double red[DDIM];
  int tid=threadIdx.x;
  b[tid]=mobs[tid];
  __syncthreads();
  for (int p=7;p>=0;p--){
    int b0=p*NB;
    for (int e=tid;e<NB*NB;e+=512){int i=e>>6,j2=e&63; D[i][j2]=Rq[(size_t)(b0+i)*DDIM+b0+j2];}
    __syncthreads();
    if (tid<64){
      double bi=b[b0+tid];
      for (int k=NB-1;k>=0;k--){
        double bk=__shfl(bi,k);
        double xk=bk/D[k][k];
        if (tid<k) bi-=D[tid][k]*xk;
        if (tid==k) bi=xk;
      }
      xs[b0+tid]=bi;
    }
    __syncthreads();
    if (tid<b0){
      double s=0;
      #pragma unroll 8
      for (int j2=0;j2<NB;j2++) s+=Rq[(size_t)tid*DDIM+b0+j2]*xs[b0+j2];
      b[tid]-=s;
    }
    __syncthreads();
  }
  red[tid]=xs[tid]*xs[tid]; __syncthreads();
  for (int s=256;s>0;s>>=1){ if (tid<s) red[tid]+=red[tid+s]; __syncthreads(); }
  double diff=sqrt(red[0]/(double)DDIM);
  if (tid==0){ scal[10]=diff; out[OUT_DIFF]=(float)diff; }
  out[OUT_ERR+tid]=(float)(diff*sqrt(fmax(g1d[tid],0.0)));
}

// X = a @ (p_inv[:,None]*l0)
__global__ void k_X(const float* a, const float* l0, const double* scal, float* X){
  int idx=blockIdx.x*blockDim.x+threadIdx.x;
  if (idx>=KDIM*KDIM) return;
  int r=idx/KDIM, c=idx%KDIM;
  int j=r/5;
  const float* arow = a + (size_t)r*KDIM + 5*j;
  double acc=0;
  for (int l=0;l<5;l++)
    acc += (double)arow[l]*scal[5+l]*(double)l0[(size_t)(5*j+l)*KDIM+c];
  X[idx]=(float)acc;
}

// ---- 64x64-tile GEMM, 4x4 per thread, fp64 accumulate ----
// A: ATR? (K x M row-major) : (M x K row-major). B: BTR? (N x K) : (K x N).
// MODE 0: double C = acc; 1: double C -= acc; 2: float C = acc.
// kmode 0: [0,K); 1: ks=n0; 2: ke=min(K,n0+64)
template<typename TA,int ATR,typename TB,int BTR,int MODE>
__global__ __launch_bounds__(256) void gemm64(const TA* __restrict__ A,int lda,
                                              const TB* __restrict__ B,int ldb,
                                              void* __restrict__ Cv,int ldc,
                                              int K,int kmode){
  __shared__ double As[16][65];
  __shared__ double Bs[16][65];
  int tid=threadIdx.x, tx=tid&15, ty=tid>>4;
  int n0=blockIdx.x*64, m0=blockIdx.y*64;
  int ks=0, ke=K;
  if (kmode==1) ks=n0;
  else if (kmode==2) ke=min(K,n0+64);
  double acc[4][4]={};
  for (int k0=ks;k0<ke;k0+=16){
    if (ATR){
      for (int e=tid;e<16*64;e+=256){int k=e>>6,mm=e&63; As[k][mm]=(double)A[(size_t)(k0+k)*lda+m0+mm];}
    } else {
      for (int e=tid;e<64*16;e+=256){int mm=e>>4,k=e&15; As[k][mm]=(double)A[(size_t)(m0+mm)*lda+k0+k];}
    }
    if (BTR){
      for (int e=tid;e<64*16;e+=256){int nn=e>>4,k=e&15; Bs[k][nn]=(double)B[(size_t)(n0+nn)*ldb+k0+k];}
    } else {
      for (int e=tid;e<16*64;e+=256){int k=e>>6,nn=e&63; Bs[k][nn]=(double)B[(size_t)(k0+k)*ldb+n0+nn];}
    }
    __syncthreads();
    #pragma unroll
    for (int t=0;t<16;t++){
      double av[4],bv[4];
      #pragma unroll
      for (int i=0;i<4;i++){av[i]=As[t][ty+16*i];bv[i]=Bs[t][tx+16*i];}
      #pragma unroll
      for (int i=0;i<4;i++)
        #pragma unroll
        for (int j=0;j<4;j++) acc[i][j]+=av[i]*bv[j];
    }
    __syncthreads();
  }
  #pragma unroll
  for (int i=0;i<4;i++){
    #pragma unroll
    for (int j=0;j<4;j++){
      size_t idx=(size_t)(m0+ty+16*i)*ldc+n0+tx+16*j;
      if (MODE==0) ((double*)Cv)[idx]=acc[i][j];
      else if (MODE==1) ((double*)Cv)[idx]-=acc[i][j];
      else ((float*)Cv)[idx]=(float)acc[i][j];
    }
  }
}

// G (lower tiles) = X X^T, exploiting X[r,c]=0 for c >= 5*(r/5)+5
__global__ __launch_bounds__(256) void syrk_lower(const float* __restrict__ X, double* __restrict__ G, int n){
  int S0=blockIdx.x*64, R0=blockIdx.y*64;
  if (S0>R0) return;
  __shared__ double As[16][65];
  __shared__ double Bs[16][65];
  int tid=threadIdx.x, tx=tid&15, ty=tid>>4;
  int kend=min(n, S0+80);
  double acc[4][4]={};
  for (int k0=0;k0<kend;k0+=16){
    for (int e=tid;e<64*16;e+=256){int mm=e>>4,k=e&15; As[k][mm]=(double)X[(size_t)(R0+mm)*n+k0+k];}
    for (int e=tid;e<64*16;e+=256){int nn=e>>4,k=e&15; Bs[k][nn]=(double)X[(size_t)(S0+nn)*n+k0+k];}
    __syncthreads();
    #pragma unroll
    for (int t=0;t<16;t++){
      double av[4],bv[4];
      #pragma unroll
      for (int i=0;i<4;i++){av[i]=As[t][ty+16*i];bv[i]=Bs[t][tx+16*i];}
      #pragma unroll
      for (int i=0;i<4;i++)
        #pragma unroll
        for (int j=0;j<4;j++) acc[i][j]+=av[i]*bv[j];
    }
    __syncthreads();
  }
  #pragma unroll
  for (int i=0;i<4;i++)
    #pragma unroll
    for (int j=0;j<4;j++)
      G[(size_t)(R0+ty+16*i)*n+S0+tx+16*j]=acc[i][j];
}

__global__ void k_addqqt(const float* q, const double* scal, double* G2){
  int idx=blockIdx.x*blockDim.x+threadIdx.x;
  if (idx>=DDIM*15) return;
  int j=idx/15, t=idx%15;
  int i=0; while (t >= i+1){ t-=i+1; i++; }
  int jj=t;
  double acc=0;
  for (int k=0;k<5;k++) acc += (double)q[(size_t)i*KDIM+k]*(double)q[(size_t)jj*KDIM+k];
  double dd=scal[10]*scal[10];
  G2[(size_t)(5*j+i)*KDIM + 5*j+jj] += dd*acc;
}

// ---- blocked Cholesky ----
__global__ __launch_bounds__(256) void chol_diag(double* A, int n, int k0){
  __shared__ double P[NB][NB+1];
  int tid=threadIdx.x;
  for (int e=tid;e<NB*NB;e+=256){int r=e>>6,c=e&63;P[r][c]=A[(size_t)(k0+r)*n+k0+c];}
  int tx=tid&15, ty=tid>>4;
  __syncthreads();
  for (int j=0;j<NB;j++){
    double pj=P[j][j];
    __syncthreads();
    double rpj=1.0/sqrt(fmax(pj,1e-280));
    if (tid>j && tid<NB) P[tid][j]*=rpj;
    if (tid==j) P[j][j]=sqrt(fmax(pj,1e-280));
    __syncthreads();
    #pragma unroll
    for (int a2=0;a2<4;a2++){
      int r=ty+16*a2;
      double lrj=P[r][j];
      #pragma unroll
      for (int b2=0;b2<4;b2++){
        int c=tx+16*b2;
        if (r>j && c>j && c<=r) P[r][c]-=lrj*P[c][j];
      }
    }
    __syncthreads();
  }
  for (int e=tid;e<NB*NB;e+=256){int r=e>>6,c=e&63;A[(size_t)(k0+r)*n+k0+c]=P[r][c];}
}

// rows below panel: Ar = Ar * Lbb^{-T}; LDS-staged coalesced loads, register solve
__global__ __launch_bounds__(256) void chol_trsm(double* A,int n,int k0){
  __shared__ double Ls[NB][NB+1];
  __shared__ double St[NB][NB+1];
  __shared__ double rec[NB];
  int tid=threadIdx.x;
  for (int e=tid;e<NB*NB;e+=256){int r=e>>6,c=e&63;Ls[r][c]=A[(size_t)(k0+r)*n+k0+c];}
  __syncthreads();
  if (tid<NB) rec[tid]=1.0/Ls[tid][tid];
  int base=k0+NB+blockIdx.x*256;
  int myrow=base+tid;
  int mychunk=tid>>6, lrow=tid&63;
  double ar[NB];
  for (int ch=0;ch<4;ch++){
    int r0=base+ch*64;
    for (int e=tid;e<NB*NB;e+=256){
      int r=e>>6,c=e&63;
      if (r0+r<n) St[r][c]=A[(size_t)(r0+r)*n+k0+c];
    }
    __syncthreads();
    if (mychunk==ch && myrow<n){
      #pragma unroll
      for (int c=0;c<NB;c++) ar[c]=St[lrow][c];
    }
    __syncthreads();
  }
  if (myrow<n){
    #pragma unroll
    for (int j=0;j<NB;j++){
      double s=ar[j];
      #pragma unroll
      for (int t=0;t<j;t++) s-=ar[t]*Ls[j][t];
      ar[j]=s*rec[j];
    }
  }
  for (int ch=0;ch<4;ch++){
    int r0=base+ch*64;
    if (mychunk==ch && myrow<n){
      #pragma unroll
      for (int c=0;c<NB;c++) St[lrow][c]=ar[c];
    }
    __syncthreads();
    for (int e=tid;e<NB*NB;e+=256){
      int r=e>>6,c=e&63;
      if (r0+r<n) A[(size_t)(r0+r)*n+k0+c]=St[r][c];
    }
    __syncthreads();
  }
}

// trailing syrk update: A_trail -= P P^T (64-wide K), 64x64 tiles, skip upper
__global__ __launch_bounds__(256) void chol_syrk(double* A,int n,int k0){
  int ts0=k0+NB;
  int S0=ts0+blockIdx.x*64, R0=ts0+blockIdx.y*64;
  if (S0>R0) return;
  __shared__ double As[16][65];
  __shared__ double Bs[16][65];
  int tid=threadIdx.x, tx=tid&15, ty=tid>>4;
  double acc[4][4]={};
  for (int k0i=0;k0i<NB;k0i+=16){
    for (int e=tid;e<64*16;e+=256){int mm=e>>4,k=e&15; As[k][mm]=A[(size_t)(R0+mm)*n+k0+k0i+k];}
    for (int e=tid;e<64*16;e+=256){int nn=e>>4,k=e&15; Bs[k][nn]=A[(size_t)(S0+nn)*n+k0+k0i+k];}
    __syncthreads();
    #pragma unroll
    for (int t=0;t<16;t++){
      double av[4],bv[4];
      #pragma unroll
      for (int i=0;i<4;i++){av[i]=As[t][ty+16*i];bv[i]=Bs[t][tx+16*i];}
      #pragma unroll
      for (int i=0;i<4;i++)
        #pragma unroll
        for (int j=0;j<4;j++) acc[i][j]+=av[i]*bv[j];
    }
    __syncthreads();
  }
  #pragma unroll
  for (int i=0;i<4;i++)
    #pragma unroll
    for (int j=0;j<4;j++)
      A[(size_t)(R0+ty+16*i)*n+S0+tx+16*j]-=acc[i][j];
}

static void chol_blocked(double* A, int n, hipStream_t stream){
  for (int k0=0;k0<n;k0+=NB){
    chol_diag<<<1,256,0,stream>>>(A,n,k0);
    int m = n-k0-NB;
    if (m>0){
      chol_trsm<<<(m+255)/256,256,0,stream>>>(A,n,k0);
      chol_syrk<<<dim3(m/64,m/64),256,0,stream>>>(A,n,k0);
    }
  }
}

// l_ext (f32) = p[:,None] * chol(G2), zero strict upper
__global__ void k_extract(const double* G2, const double* scal, float* lext){
  int idx=blockIdx.x*blockDim.x+threadIdx.x;
  if (idx>=KDIM*KDIM) return;
  int r=idx/KDIM, c=idx%KDIM;
  double v = (c<=r)? scal[r%5]*G2[idx] : 0.0;
  lext[idx]=(float)v;
}

// ---- multi-RHS blocked triangular solves on Z (DDIM x KDIM) ----
__global__ __launch_bounds__(256) void trsm_fwd(const double* __restrict__ L,int n,int b0,
                                                double* __restrict__ Z,int ldz){
  __shared__ double Ls[NB][NB+1];
  __shared__ double rec[NB];
  int lin=threadIdx.x;
  for (int e=lin;e<NB*NB;e+=256){int r=e>>6,c=e&63;Ls[r][c]=L[(size_t)(b0+r)*n+b0+c];}
  __syncthreads();
  if (lin<NB) rec[lin]=1.0/Ls[lin][lin];
  __syncthreads();
  int col=blockIdx.x*256+lin;
  double z[NB];
  #pragma unroll
  for (int r=0;r<NB;r++) z[r]=Z[(size_t)(b0+r)*ldz+col];
  #pragma unroll
  for (int r=0;r<NB;r++){
    double s=z[r];
    #pragma unroll
    for (int t=0;t<r;t++) s-=Ls[r][t]*z[t];
    z[r]=s*rec[r];
  }
  #pragma unroll
  for (int r=0;r<NB;r++) Z[(size_t)(b0+r)*ldz+col]=z[r];
}

__global__ __launch_bounds__(256) void trsm_bwd(const double* __restrict__ L,int n,int b0,
                                                double* __restrict__ Z,int ldz){
  __shared__ double Ls[NB][NB+1];
  __shared__ double rec[NB];
  int lin=threadIdx.x;
  for (int e=lin;e<NB*NB;e+=256){int r=e>>6,c=e&63;Ls[r][c]=L[(size_t)(b0+r)*n+b0+c];}
  __syncthreads();
  if (lin<NB) rec[lin]=1.0/Ls[lin][lin];
  __syncthreads();
  int col=blockIdx.x*256+lin;
  double z[NB];
  #pragma unroll
  for (int r=0;r<NB;r++) z[r]=Z[(size_t)(b0+r)*ldz+col];
  #pragma unroll
  for (int ri=NB-1;ri>=0;ri--){
    double s=z[ri];
    #pragma unroll
    for (int t=ri+1;t<NB;t++) s-=Ls[t][ri]*z[t];
    z[ri]=s*rec[ri];
  }
  #pragma unroll
  for (int r=0;r<NB;r++) Z[(size_t)(b0+r)*ldz+col]=z[r];
}

// m_cor = m_ext - Z^T @ m_obs; also u
__global__ void k_mcor(const double* Z, const double* mobs, const double* mext, float* out){
  __shared__ double mo[DDIM];
  for (int s=threadIdx.x;s<DDIM;s+=256) mo[s]=mobs[s];
  __syncthreads();
  int r=blockIdx.x*256+threadIdx.x;
  if (r>=KDIM) return;
  double acc=0;
  for (int s=0;s<DDIM;s++) acc += Z[(size_t)s*KDIM+r]*mo[s];
  double mc = mext[r]-acc;
  out[r]=(float)mc;
  if (r%5==0) out[OUT_U + r/5]=(float)mc;
}

// l_cor = l_ext - Z^T @ l_obs_ns (64x64 tiles)
__global__ __launch_bounds__(256) void k_lcor(const double* __restrict__ Z, const float* __restrict__ lobs,
                                              const float* __restrict__ lext, float* __restrict__ out){
  __shared__ double As[16][65];
  __shared__ double Bs[16][65];
  int tid=threadIdx.x, tx=tid&15, ty=tid>>4;
  int n0=blockIdx.x*64, m0=blockIdx.y*64;
  double acc[4][4]={};
  for (int k0=0;k0<DDIM;k0+=16){
    for (int e=tid;e<16*64;e+=256){int k=e>>6,mm=e&63; As[k][mm]=Z[(size_t)(k0+k)*KDIM+m0+mm];}
    for (int e=tid;e<16*64;e+=256){int k=e>>6,nn=e&63; Bs[k][nn]=(double)lobs[(size_t)(k0+k)*KDIM+n0+nn];}
    __syncthreads();
    #pragma unroll
    for (int t=0;t<16;t++){
      double av[4],bv[4];
      #pragma unroll
      for (int i=0;i<4;i++){av[i]=As[t][ty+16*i];bv[i]=Bs[t][tx+16*i];}
      #pragma unroll
      for (int i=0;i<4;i++)
        #pragma unroll
        for (int j=0;j<4;j++) acc[i][j]+=av[i]*bv[j];
    }
    __syncthreads();
  }
  #pragma unroll
  for (int i=0;i<4;i++)
    #pragma unroll
    for (int j=0;j<4;j++){
      size_t idx=(size_t)(m0+ty+16*i)*KDIM+n0+tx+16*j;
      out[OUT_LCOR+idx]=(float)((double)lext[idx]-acc[i][j]);
    }
}

extern "C" void kernel_launch(void* const* d_in, const int* in_sizes, int n_in,
                              void* d_out, int out_size, void* d_ws, size_t ws_size,
                              hipStream_t stream) {
  const float* m0  = (const float*)d_in[0];
  const float* l0  = (const float*)d_in[1];
  const float* H   = (const float*)d_in[2];
  const float* bias= (const float*)d_in[3];
  const float* dt  = (const float*)d_in[4];
  const float* a   = (const float*)d_in[5];
  const float* q   = (const float*)d_in[6];
  float* out = (float*)d_out;

  char* w=(char*)d_ws;
  auto alloc=[&](size_t bytes)->char*{ char* p=w; w += ((bytes+255)/256)*256; return p; };
  double* scal =(double*)alloc(16*8);
  double* mext =(double*)alloc((size_t)KDIM*8);
  double* mobs =(double*)alloc((size_t)DDIM*8);
  double* g1d  =(double*)alloc((size_t)DDIM*8);
  double* betaA=(double*)alloc((size_t)QN*8);
  double* vheadA=(double*)alloc((size_t)QN*8);
  double* Tbuf =(double*)alloc((size_t)PW*PW*8);
  double* Aq   =(double*)alloc((size_t)QM*QN*8);     // QR working matrix (fp64)
  double* Rq   =(double*)alloc((size_t)QN*QN*8);     // R factor
  double* S    =(double*)alloc((size_t)DDIM*DDIM*8); // innovation Gram + chol
  double* G2   =(double*)alloc((size_t)KDIM*KDIM*8); // big Gram -> chol; reused as Z
  float*  LOBS =(float*) alloc((size_t)DDIM*KDIM*4);
  float*  X    =(float*) alloc((size_t)KDIM*KDIM*4); // X; later l_ext
  double* Z    = G2;       // fp64 DDIM x KDIM, alias after k_extract
  float*  LEXT = X;

  // ---- extrapolate mean, observe ----
  k_setup<<<1,1,0,stream>>>(dt, scal);
  k_mext<<<(KDIM+255)/256,256,0,stream>>>(a, m0, scal, mext);
  k_mobs<<<DDIM,256,0,stream>>>(H, bias, mext, mobs);

  // ---- first QR: Householder fp64, LAPACK signs ----
  k_A<<<(QN*QM+255)/256,256,0,stream>>>(H, q, scal, Aq);
  for (int p=0;p<QN/PW;p++){
    int col0=p*PW;
    qr_panel<<<1,1024,0,stream>>>(Aq, betaA, vheadA, col0);
    int ntr = QN - col0 - PW;
    if (ntr>0){
      qr_vtvT<<<1,512,0,stream>>>(Aq,betaA,vheadA,col0,Tbuf);
      qr_update<<<ntr,256,0,stream>>>(Aq, vheadA, Tbuf, col0);
    }
  }
  k_extractR<<<(QN*QN+255)/256,256,0,stream>>>(Aq, Rq);
  k_colnorm<<<(QN+255)/256,256,0,stream>>>(Rq, g1d);
  k_resw<<<1,512,0,stream>>>(Rq, mobs, g1d, scal, out);

  // ---- extrapolated covariance sqrt via Gram + Cholesky ----
  k_X<<<(KDIM*KDIM+255)/256,256,0,stream>>>(a, l0, scal, X);
  syrk_lower<<<dim3(KDIM/64,KDIM/64),256,0,stream>>>(X, G2, KDIM);
  k_addqqt<<<(DDIM*15+255)/256,256,0,stream>>>(q, scal, G2);
  chol_blocked(G2, KDIM, stream);
  k_extract<<<(KDIM*KDIM+255)/256,256,0,stream>>>(G2, scal, LEXT);  // G2 dead -> Z

  // ---- correction ----
  // LOBS = H @ LEXT (LEXT lower-triangular: k starts at n0)
  gemm64<float,0,float,0,2><<<dim3(KDIM/64,DDIM/64),256,0,stream>>>(H,KDIM, LEXT,KDIM, LOBS,KDIM, KDIM, 1);
  // S = LOBS @ LOBS^T
  gemm64<float,0,float,1,0><<<dim3(DDIM/64,DDIM/64),256,0,stream>>>(LOBS,KDIM, LOBS,KDIM, S,DDIM, KDIM, 0);
  chol_blocked(S, DDIM, stream);
  // Z = LOBS @ LEXT^T  (crosscov^T; LEXT rows n0..n0+63 nonzero only k<n0+64)
  gemm64<float,0,float,1,0><<<dim3(KDIM/64,DDIM/64),256,0,stream>>>(LOBS,KDIM, LEXT,KDIM, Z,KDIM, KDIM, 2);
  // cho_solve: Z <- L^{-1} Z ; Z <- L^{-T} Z  (then gain = Z^T)
  for (int b=0;b<DDIM;b+=NB){
    trsm_fwd<<<KDIM/256,256,0,stream>>>(S, DDIM, b, Z, KDIM);
    int m = DDIM-b-NB;
    if (m>0)
      gemm64<double,0,double,0,1><<<dim3(KDIM/64,m/64),256,0,stream>>>(
        S+(size_t)(b+NB)*DDIM+b, DDIM, Z+(size_t)b*KDIM, KDIM,
        Z+(size_t)(b+NB)*KDIM, KDIM, NB, 0);
  }
  for (int b=DDIM-NB;b>=0;b-=NB){
    trsm_bwd<<<KDIM/256,256,0,stream>>>(S, DDIM, b, Z, KDIM);
    if (b>0)
      gemm64<double,1,double,0,1><<<dim3(KDIM/64,b/64),256,0,stream>>>(
        S+(size_t)b*DDIM, DDIM, Z+(size_t)b*KDIM, KDIM,
        Z, KDIM, NB, 0);
  }

  k_mcor<<<(KDIM+255)/256,256,0,stream>>>(Z, mobs, mext, out);
  k_lcor<<<dim3(KDIM/64,KDIM/64),256,0,stream>>>(Z, LOBS, LEXT, out);
}

// Round 6
// 17140.547 us; speedup vs baseline: 1.5896x; 1.0610x over previous
//
#include <hip/hip_runtime.h>
#include <math.h>

#define KDIM 2560
#define DDIM 512
#define NB 64

#define QM 2560
#define QN 512
#define PW 16
#define UW 10

// out layout (floats): m_cor @0 (2560), l_cor @2560 (2560*2560), u @6556160 (512),
// error @6556672 (512), diffusion @6557184 (1)
#define OUT_LCOR 2560
#define OUT_U    6556160
#define OUT_ERR  6556672
#define OUT_DIFF 6557184

// scal: [10] = diffusion (runtime value); p/pinv patterns computed inline from dt

__device__ __forceinline__ void get_pats(const float* dt, double* pp, double* pv){
  double adt = fabs((double)dt[0]);
  const double scales[5] = {24.0,6.0,2.0,1.0,1.0};
  #pragma unroll
  for (int i=0;i<5;i++){
    double pw = (double)(4-i)+0.5;
    pp[i] = pow(adt, pw)/scales[i];
    pv[i] = pow(adt,-pw)*scales[i];
  }
}

// fused: mext (block 0 writes) + mobs (one block per row)
__global__ __launch_bounds__(256) void k_mext_mobs(const float* a, const float* m0, const float* H,
                                                   const float* bias, const float* dt,
                                                   double* mext, double* mobs){
  __shared__ double me[KDIM];
  __shared__ double red[256];
  double pp[5], pv[5];
  get_pats(dt, pp, pv);
  int tid=threadIdx.x;
  for (int r=tid; r<KDIM; r+=256){
    int j=r/5, i=r%5;
    const float* arow = a + (size_t)r*KDIM + 5*j;
    const float* m0b  = m0 + 5*j;
    double acc=0;
    #pragma unroll
    for (int l=0;l<5;l++) acc += (double)arow[l]*pv[l]*(double)m0b[l];
    me[r] = pp[i]*acc;
  }
  __syncthreads();
  if (blockIdx.x==0) for (int r=tid;r<KDIM;r+=256) mext[r]=me[r];
  int b = blockIdx.x;
  const float* Hr = H + (size_t)b*KDIM;
  double acc=0;
  for (int c=tid;c<KDIM;c+=256) acc += (double)Hr[c]*me[c];
  red[tid]=acc; __syncthreads();
  for (int s=128;s>0;s>>=1){ if (tid<s) red[tid]+=red[tid+s]; __syncthreads(); }
  if (tid==0) mobs[b] = red[0] - (double)bias[b];
}

// A (col-major QM x QN) = (H @ (p_inv[:,None]*q)).T in fp64
__global__ void k_A(const float* H, const float* q, const float* dt, double* A){
  int idx = blockIdx.x*blockDim.x+threadIdx.x;
  if (idx >= QN*QM) return;
  double pp[5], pv[5];
  get_pats(dt, pp, pv);
  int j = idx / QM;
  int i = idx % QM;
  int bi = i/5;
  double acc=0;
  #pragma unroll
  for (int t=0;t<5;t++)
    acc += (double)H[(size_t)j*QM + 5*bi+t]*pv[t]*(double)q[(size_t)(5*bi+t)*QM + i];
  A[idx] = acc;
}

// ---- Householder QR (LAPACK signs), LDS panel + fused incremental VtV / T build ----
__global__ __launch_bounds__(1024) void qr_panel(double* A, double* vhead, int col0, double* Tbuf){
  __shared__ double vbuf[QM];
  __shared__ double red[1024];
  __shared__ double sh[2];
  __shared__ double VtVs[PW][PW];
  __shared__ double betas_s[PW];
  __shared__ double Tsh[PW][PW];
  int tid = threadIdx.x;
  int wid = tid >> 6, lane = tid & 63;
  for (int j=0;j<PW;j++){
    int c = col0 + j;
    double acc = 0;
    for (int r = c + tid; r < QM; r += 1024){
      double v = A[(size_t)c*QM + r];
      vbuf[r-c] = v;
      acc += v*v;
    }
    red[tid] = acc; __syncthreads();
    for (int s=512; s>0; s>>=1){ if (tid<s) red[tid]+=red[tid+s]; __syncthreads(); }
    if (tid==0){
      double s0 = red[0];
      double x1 = vbuf[0];
      double nrm = sqrt(s0);
      double alpha = (x1 >= 0.0) ? -nrm : nrm;   // LAPACK: R_cc = -sign(x1)*||x||
      double v1 = x1 - alpha;
      double vtv = s0 - 2.0*alpha*x1 + alpha*alpha;
      double b = (vtv > 0.0) ? 2.0/vtv : 0.0;
      vbuf[0] = v1;
      sh[0] = b;
      A[(size_t)c*QM + c] = alpha;
      betas_s[j] = b;
      vhead[c] = v1;
    }
    __syncthreads();
    double b = sh[0];
    // trailing in-panel update (wave per trailing column)
    int jj = j + 1 + wid;
    if (jj < PW && b != 0.0){
      int cc = col0 + jj;
      double d = 0;
      for (int r = c + lane; r < QM; r += 64)
        d += vbuf[r-c]*A[(size_t)cc*QM + r];
      #pragma unroll
      for (int off=32; off>0; off>>=1) d += __shfl_down(d, off);
      d = __shfl(d, 0);
      double sc = b*d;
      for (int r = c + lane; r < QM; r += 64)
        A[(size_t)cc*QM + r] -= sc*vbuf[r-c];
    }
    // fused VtV: v_i . v_j for i<j (v_j in vbuf; rows >= c so v_i entries plain A)
    if (wid < j){
      int i = wid;
      double d = 0;
      for (int r = c + lane; r < QM; r += 64)
        d += vbuf[r-c]*A[(size_t)(col0+i)*QM + r];
      #pragma unroll
      for (int off=32; off>0; off>>=1) d += __shfl_down(d, off);
      if (lane==0) VtVs[i][j] = d;
    }
    __syncthreads();
  }
  if (tid==0){
    for (int j=0;j<PW;j++){
      double bj = betas_s[j];
      Tsh[j][j] = bj;
      for (int i=0;i<j;i++){
        double z=0;
        for (int t=i;t<j;t++) z += Tsh[i][t]*VtVs[t][j];
        Tsh[i][j] = -bj*z;
      }
    }
  }
  __syncthreads();
  for (int e=tid;e<PW*PW;e+=1024){
    int i=e/PW, j2=e%PW;
    Tbuf[e] = (j2>=i)? Tsh[i][j2] : 0.0;
  }
}

// fused trailing update: a_cc -= V * (T^T (V^T a_cc)); one block per trailing column
__global__ __launch_bounds__(256) void qr_update(double* A, const double* vhead,
                                                 const double* Tbuf, int col0){
  __shared__ double redu[4][PW];
  __shared__ double ysh[PW];
  __shared__ double wsh[PW];
  int tid=threadIdx.x, wid=tid>>6, lane=tid&63;
  int cc=col0+PW+blockIdx.x;
  int m=QM-col0;
  double a[UW];
  #pragma unroll
  for (int w=0;w<UW;w++){
    int lr=tid+w*256;
    a[w]=(lr<m)? A[(size_t)cc*QM+col0+lr] : 0.0;
  }
  double acc[PW];
  #pragma unroll
  for (int j=0;j<PW;j++) acc[j]=0;
  #pragma unroll
  for (int w=0;w<UW;w++){
    int lr=tid+w*256;
    if (lr<m){
      #pragma unroll
      for (int j=0;j<PW;j++){
        double vj;
        if (lr>j)       vj=A[(size_t)(col0+j)*QM+col0+lr];
        else if (lr==j) vj=vhead[col0+j];
        else            vj=0.0;
        acc[j]+=vj*a[w];
      }
    }
  }
  #pragma unroll
  for (int j=0;j<PW;j++){
    double d=acc[j];
    #pragma unroll
    for (int o=32;o>0;o>>=1) d+=__shfl_down(d,o);
    if (lane==0) redu[wid][j]=d;
  }
  __syncthreads();
  if (tid<PW){
    double y=0;
    #pragma unroll
    for (int t=0;t<4;t++) y+=redu[t][tid];
    ysh[tid]=y;
  }
  __syncthreads();
  if (tid<PW){
    double s=0;
    for (int t=0;t<=tid;t++) s+=Tbuf[t*PW+tid]*ysh[t];
    wsh[tid]=s;
  }
  __syncthreads();
  #pragma unroll
  for (int w=0;w<UW;w++){
    int lr=tid+w*256;
    if (lr<m){
      double s=0;
      #pragma unroll
      for (int j=0;j<PW;j++){
        double vj;
        if (lr>j)       vj=A[(size_t)(col0+j)*QM+col0+lr];
        else if (lr==j) vj=vhead[col0+j];
        else            vj=0.0;
        s+=vj*wsh[j];
      }
      A[(size_t)cc*QM+col0+lr]=a[w]-s;
    }
  }
}

// fused: R column norms + backward solve R x = m_obs + diffusion + error (reads R from Aq)
__global__ __launch_bounds__(512) void k_rpost(const double* Aq, const double* mobs,
                                               double* scal, float* out){
  __shared__ double b[DDIM];
  __shared__ double xs[DDIM];
  __shared__ double D[NB][NB+1];
  __shared__ double red[DDIM];
  __shared__ double g1sh[DDIM];
  int tid=threadIdx.x;
  {
    double s=0;
    for (int r=0;r<=tid;r++){ double v=Aq[(size_t)tid*QM + r]; s+=v*v; }
    g1sh[tid]=s;
  }
  b[tid]=mobs[tid];
  __syncthreads();
  for (int p=7;p>=0;p--){
    int b0=p*NB;
    for (int e=tid;e<NB*NB;e+=512){ int i=e&63, j2=e>>6; D[i][j2]=Aq[(size_t)(b0+j2)*QM + b0+i]; }
    __syncthreads();
    if (tid<64){
      double bi=b[b0+tid];
      for (int k=NB-1;k>=0;k--){
        double bk=__shfl(bi,k);
        double xk=bk/D[k][k];
        if (tid<k) bi-=D[tid][k]*xk;
        if (tid==k) bi=xk;
      }
      xs[b0+tid]=bi;
    }
    __syncthreads();
    if (tid<b0){
      double s=0;
      #pragma unroll 8
      for (int j2=0;j2<NB;j2++) s+=Aq[(size_t)(b0+j2)*QM + tid]*xs[b0+j2];
      b[tid]-=s;
    }
    __syncthreads();
  }
  red[tid]=xs[tid]*xs[tid]; __syncthreads();
  for (int s=256;s>0;s>>=1){ if (tid<s) red[tid]+=red[tid+s]; __syncthreads(); }
  double diff=sqrt(red[0]/(double)DDIM);
  if (tid==0){ scal[10]=diff; out[OUT_DIFF]=(float)diff; }
  out[OUT_ERR+tid]=(float)(diff*sqrt(fmax(g1sh[tid],0.0)));
}

// X = a @ (p_inv[:,None]*l0)
__global__ void k_X(const float* a, const float* l0, const float* dt, float* X){
  int idx=blockIdx.x*blockDim.x+threadIdx.x;
  if (idx>=KDIM*KDIM) return;
  double pp[5], pv[5];
  get_pats(dt, pp, pv);
  int r=idx/KDIM, c=idx%KDIM;
  int j=r/5;
  const float* arow = a + (size_t)r*KDIM + 5*j;
  double acc=0;
  #pragma unroll
  for (int l=0;l<5;l++)
    acc += (double)arow[l]*pv[l]*(double)l0[(size_t)(5*j+l)*KDIM+c];
  X[idx]=(float)acc;
}

// ---- 64x64-tile GEMM, 4x4 per thread, fp64 accumulate ----
// A: ATR? (K x M row-major) : (M x K). B: BTR? (N x K) : (K x N).
// MODE 0: double C = acc; 1: double C -= acc; 2: float C = acc.
// kmode 0: [0,K); 1: ks=n0; 2: ke=min(K,n0+64); 3: ke=min(K,m0+64); 4: ks=m0
template<typename TA,int ATR,typename TB,int BTR,int MODE>
__global__ __launch_bounds__(256) void gemm64(const TA* __restrict__ A,int lda,
                                              const TB* __restrict__ B,int ldb,
                                              void* __restrict__ Cv,int ldc,
                                              int K,int kmode){
  __shared__ double As[16][65];
  __shared__ double Bs[16][65];
  int tid=threadIdx.x, tx=tid&15, ty=tid>>4;
  int n0=blockIdx.x*64, m0=blockIdx.y*64;
  int ks=0, ke=K;
  if (kmode==1) ks=n0;
  else if (kmode==2) ke=min(K,n0+64);
  else if (kmode==3) ke=min(K,m0+64);
  else if (kmode==4) ks=m0;
  double acc[4][4]={};
  for (int k0=ks;k0<ke;k0+=16){
    if (ATR){
      for (int e=tid;e<16*64;e+=256){int k=e>>6,mm=e&63; As[k][mm]=(double)A[(size_t)(k0+k)*lda+m0+mm];}
    } else {
      for (int e=tid;e<64*16;e+=256){int mm=e>>4,k=e&15; As[k][mm]=(double)A[(size_t)(m0+mm)*lda+k0+k];}
    }
    if (BTR){
      for (int e=tid;e<64*16;e+=256){int nn=e>>4,k=e&15; Bs[k][nn]=(double)B[(size_t)(n0+nn)*ldb+k0+k];}
    } else {
      for (int e=tid;e<16*64;e+=256){int k=e>>6,nn=e&63; Bs[k][nn]=(double)B[(size_t)(k0+k)*ldb+n0+nn];}
    }
    __syncthreads();
    #pragma unroll
    for (int t=0;t<16;t++){
      double av[4],bv[4];
      #pragma unroll
      for (int i=0;i<4;i++){av[i]=As[t][ty+16*i];bv[i]=Bs[t][tx+16*i];}
      #pragma unroll
      for (int i=0;i<4;i++)
        #pragma unroll
        for (int j=0;j<4;j++) acc[i][j]+=av[i]*bv[j];
    }
    __syncthreads();
  }
  #pragma unroll
  for (int i=0;i<4;i++){
    #pragma unroll
    for (int j=0;j<4;j++){
      size_t idx=(size_t)(m0+ty+16*i)*ldc+n0+tx+16*j;
      if (MODE==0) ((double*)Cv)[idx]=acc[i][j];
      else if (MODE==1) ((double*)Cv)[idx]-=acc[i][j];
      else ((float*)Cv)[idx]=(float)acc[i][j];
    }
  }
}

// G (lower tiles) = X X^T (band-limited) + fused diffusion^2 * kron(I, L1 L1^T)
__global__ __launch_bounds__(256) void syrk_lower(const float* __restrict__ X, const float* __restrict__ q,
                                                  const double* __restrict__ scal,
                                                  double* __restrict__ G, int n){
  int S0=blockIdx.x*64, R0=blockIdx.y*64;
  if (S0>R0) return;
  __shared__ double As[16][65];
  __shared__ double Bs[16][65];
  int tid=threadIdx.x, tx=tid&15, ty=tid>>4;
  int kend=min(n, S0+80);
  double acc[4][4]={};
  for (int k0=0;k0<kend;k0+=16){
    for (int e=tid;e<64*16;e+=256){int mm=e>>4,k=e&15; As[k][mm]=(double)X[(size_t)(R0+mm)*n+k0+k];}
    for (int e=tid;e<64*16;e+=256){int nn=e>>4,k=e&15; Bs[k][nn]=(double)X[(size_t)(S0+nn)*n+k0+k];}
    __syncthreads();
    #pragma unroll
    for (int t=0;t<16;t++){
      double av[4],bv[4];
      #pragma unroll
      for (int i=0;i<4;i++){av[i]=As[t][ty+16*i];bv[i]=Bs[t][tx+16*i];}
      #pragma unroll
      for (int i=0;i<4;i++)
        #pragma unroll
        for (int j=0;j<4;j++) acc[i][j]+=av[i]*bv[j];
    }
    __syncthreads();
  }
  double dd = scal[10]*scal[10];
  #pragma unroll
  for (int i=0;i<4;i++)
    #pragma unroll
    for (int j=0;j<4;j++){
      int r=R0+ty+16*i, c=S0+tx+16*j;
      double v=acc[i][j];
      if (c<=r && (r/5)==(c/5)){
        double qq=0;
        #pragma unroll
        for (int k=0;k<5;k++) qq += (double)q[(size_t)(r%5)*KDIM+k]*(double)q[(size_t)(c%5)*KDIM+k];
        v += dd*qq;
      }
      G[(size_t)r*n+c]=v;
    }
}

// ---- blocked Cholesky ----
__global__ __launch_bounds__(256) void chol_diag(double* A, int n, int k0){
  __shared__ double P[NB][NB+1];
  int tid=threadIdx.x;
  for (int e=tid;e<NB*NB;e+=256){int r=e>>6,c=e&63;P[r][c]=A[(size_t)(k0+r)*n+k0+c];}
  int tx=tid&15, ty=tid>>4;
  __syncthreads();
  for (int j=0;j<NB;j++){
    double pj=P[j][j];
    __syncthreads();
    double rpj=1.0/sqrt(fmax(pj,1e-280));
    if (tid>j && tid<NB) P[tid][j]*=rpj;
    if (tid==j) P[j][j]=sqrt(fmax(pj,1e-280));
    __syncthreads();
    #pragma unroll
    for (int a2=0;a2<4;a2++){
      int r=ty+16*a2;
      double lrj=P[r][j];
      #pragma unroll
      for (int b2=0;b2<4;b2++){
        int c=tx+16*b2;
        if (r>j && c>j && c<=r) P[r][c]-=lrj*P[c][j];
      }
    }
    __syncthreads();
  }
  for (int e=tid;e<NB*NB;e+=256){int r=e>>6,c=e&63;A[(size_t)(k0+r)*n+k0+c]=P[r][c];}
}

// rows below panel: Ar = Ar * Lbb^{-T}; LDS-staged coalesced loads, register solve
__global__ __launch_bounds__(256) void chol_trsm(double* A,int n,int k0){
  __shared__ double Ls[NB][NB+1];
  __shared__ double St[NB][NB+1];
  __shared__ double rec[NB];
  int tid=threadIdx.x;
  for (int e=tid;e<NB*NB;e+=256){int r=e>>6,c=e&63;Ls[r][c]=A[(size_t)(k0+r)*n+k0+c];}
  __syncthreads();
  if (tid<NB) rec[tid]=1.0/Ls[tid][tid];
  int base=k0+NB+blockIdx.x*256;
  int myrow=base+tid;
  int mychunk=tid>>6, lrow=tid&63;
  double ar[NB];
  for (int ch=0;ch<4;ch++){
    int r0=base+ch*64;
    for (int e=tid;e<NB*NB;e+=256){
      int r=e>>6,c=e&63;
      if (r0+r<n) St[r][c]=A[(size_t)(r0+r)*n+k0+c];
    }
    __syncthreads();
    if (mychunk==ch && myrow<n){
      #pragma unroll
      for (int c=0;c<NB;c++) ar[c]=St[lrow][c];
    }
    __syncthreads();
  }
  if (myrow<n){
    #pragma unroll
    for (int j=0;j<NB;j++){
      double s=ar[j];
      #pragma unroll
      for (int t=0;t<j;t++) s-=ar[t]*Ls[j][t];
      ar[j]=s*rec[j];
    }
  }
  for (int ch=0;ch<4;ch++){
    int r0=base+ch*64;
    if (mychunk==ch && myrow<n){
      #pragma unroll
      for (int c=0;c<NB;c++) St[lrow][c]=ar[c];
    }
    __syncthreads();
    for (int e=tid;e<NB*NB;e+=256){
      int r=e>>6,c=e&63;
      if (r0+r<n) A[(size_t)(r0+r)*n+k0+c]=St[r][c];
    }
    __syncthreads();
  }
}

// trailing syrk (64x64 tiles, skip upper) with FUSED factorization of the next
// diagonal block: block (0,0) factors tile (ts0,ts0) after applying its update.
__global__ __launch_bounds__(256) void chol_syrk_fd(double* A,int n,int k0){
  int ts0=k0+NB;
  int S0=ts0+blockIdx.x*64, R0=ts0+blockIdx.y*64;
  if (S0>R0) return;
  __shared__ double As[16][65];
  __shared__ double Bs[16][65];
  __shared__ double P[NB][NB+1];
  int tid=threadIdx.x, tx=tid&15, ty=tid>>4;
  double acc[4][4]={};
  for (int k0i=0;k0i<NB;k0i+=16){
    for (int e=tid;e<64*16;e+=256){int mm=e>>4,k=e&15; As[k][mm]=A[(size_t)(R0+mm)*n+k0+k0i+k];}
    for (int e=tid;e<64*16;e+=256){int nn=e>>4,k=e&15; Bs[k][nn]=A[(size_t)(S0+nn)*n+k0+k0i+k];}
    __syncthreads();
    #pragma unroll
    for (int t=0;t<16;t++){
      double av[4],bv[4];
      #pragma unroll
      for (int i=0;i<4;i++){av[i]=As[t][ty+16*i];bv[i]=Bs[t][tx+16*i];}
      #pragma unroll
      for (int i=0;i<4;i++)
        #pragma unroll
        for (int j=0;j<4;j++) acc[i][j]+=av[i]*bv[j];
    }
    __syncthreads();
  }
  if (!(blockIdx.x==0 && blockIdx.y==0)){
    #pragma unroll
    for (int i=0;i<4;i++)
      #pragma unroll
      for (int j=0;j<4;j++)
        A[(size_t)(R0+ty+16*i)*n+S0+tx+16*j]-=acc[i][j];
    return;
  }
  // diagonal block: update into LDS, factor, store
  #pragma unroll
  for (int i=0;i<4;i++)
    #pragma unroll
    for (int j=0;j<4;j++)
      P[ty+16*i][tx+16*j] = A[(size_t)(R0+ty+16*i)*n+S0+tx+16*j] - acc[i][j];
  __syncthreads();
  for (int j=0;j<NB;j++){
    double pj=P[j][j];
    __syncthreads();
    double rpj=1.0/sqrt(fmax(pj,1e-280));
    if (tid>j && tid<NB) P[tid][j]*=rpj;
    if (tid==j) P[j][j]=sqrt(fmax(pj,1e-280));
    __syncthreads();
    #pragma unroll
    for (int a2=0;a2<4;a2++){
      int r=ty+16*a2;
      double lrj=P[r][j];
      #pragma unroll
      for (int b2=0;b2<4;b2++){
        int c=tx+16*b2;
        if (r>j && c>j && c<=r) P[r][c]-=lrj*P[c][j];
      }
    }
    __syncthreads();
  }
  for (int e=tid;e<NB*NB;e+=256){int r=e>>6,c=e&63;A[(size_t)(ts0+r)*n+ts0+c]=P[r][c];}
}

// l_ext (f32) = p[:,None] * chol(G2), zero strict upper
__global__ void k_extract(const double* G2, const float* dt, float* lext){
  int idx=blockIdx.x*blockDim.x+threadIdx.x;
  if (idx>=KDIM*KDIM) return;
  double pp[5], pv[5];
  get_pats(dt, pp, pv);
  int r=idx/KDIM, c=idx%KDIM;
  double v = (c<=r)? pp[r%5]*G2[idx] : 0.0;
  lext[idx]=(float)v;
}

// ---- explicit blocked inverse of lower-triangular L (512) ----
// each block j: zero its 64-wide column stripe, then invert diag block in LDS
__global__ __launch_bounds__(256) void trinv_diag(const double* S, double* Linv){
  __shared__ double Ls[NB][NB+1];
  __shared__ double Ti[NB][NB+1];
  int jb=blockIdx.x, tid=threadIdx.x;
  for (int e=tid; e<DDIM*NB; e+=256){
    int r=e/NB, c=e%NB;
    Linv[(size_t)r*DDIM + jb*NB + c]=0.0;
  }
  for (int e=tid;e<NB*NB;e+=256){int r=e>>6,c=e&63; Ls[r][c]=S[(size_t)(jb*NB+r)*DDIM + jb*NB+c];}
  __syncthreads();
  if (tid<NB){
    int c=tid;
    for (int r=c;r<NB;r++){
      double s=(r==c)?1.0:0.0;
      for (int t=c;t<r;t++) s-=Ls[r][t]*Ti[t][c];
      Ti[r][c]=s/Ls[r][r];
    }
    for (int r=0;r<c;r++) Ti[r][c]=0.0;
  }
  __syncthreads();
  for (int e=tid;e<NB*NB;e+=256){int r=e>>6,c=e&63; Linv[(size_t)(jb*NB+r)*DDIM + jb*NB+c]=Ti[r][c];}
}

// Linv[i][j] = -Linv_ii * (sum_{k=j..i-1} L[i][k] Linv[k][j]), i = j+d
__global__ __launch_bounds__(256) void trinv_step(const double* S, double* Linv, int d){
  __shared__ double As[16][65];
  __shared__ double Bs[16][65];
  __shared__ double Ps[NB][NB+1];
  int jb=blockIdx.x, ib=jb+d;
  int tid=threadIdx.x, tx=tid&15, ty=tid>>4;
  double acc[4][4]={};
  int kstart=jb*NB, kend=ib*NB;
  for (int k0=kstart;k0<kend;k0+=16){
    for (int e=tid;e<64*16;e+=256){int mm=e>>4,k=e&15; As[k][mm]=S[(size_t)(ib*NB+mm)*DDIM + k0+k];}
    for (int e=tid;e<16*64;e+=256){int k=e>>6,nn=e&63; Bs[k][nn]=Linv[(size_t)(k0+k)*DDIM + jb*NB+nn];}
    __syncthreads();
    #pragma unroll
    for (int t=0;t<16;t++){
      double av[4],bv[4];
      #pragma unroll
      for (int i=0;i<4;i++){av[i]=As[t][ty+16*i];bv[i]=Bs[t][tx+16*i];}
      #pragma unroll
      for (int i=0;i<4;i++)
        #pragma unroll
        for (int j=0;j<4;j++) acc[i][j]+=av[i]*bv[j];
    }
    __syncthreads();
  }
  #pragma unroll
  for (int i=0;i<4;i++)
    #pragma unroll
    for (int j=0;j<4;j++) Ps[ty+16*i][tx+16*j]=acc[i][j];
  double o[4][4]={};
  __syncthreads();
  for (int k0=0;k0<NB;k0+=16){
    for (int e=tid;e<64*16;e+=256){int mm=e>>4,k=e&15; As[k][mm]=Linv[(size_t)(ib*NB+mm)*DDIM + ib*NB+k0+k];}
    __syncthreads();
    #pragma unroll
    for (int t=0;t<16;t++){
      double av[4],bv[4];
      #pragma unroll
      for (int i=0;i<4;i++){av[i]=As[t][ty+16*i];bv[i]=Ps[k0+t][tx+16*i];}
      #pragma unroll
      for (int i=0;i<4;i++)
        #pragma unroll
        for (int j=0;j<4;j++) o[i][j]+=av[i]*bv[j];
    }
    __syncthreads();
  }
  #pragma unroll
  for (int i=0;i<4;i++)
    #pragma unroll
    for (int j=0;j<4;j++)
      Linv[(size_t)(ib*NB+ty+16*i)*DDIM + jb*NB+tx+16*j] = -o[i][j];
}

// m_cor = m_ext - Z^T @ m_obs; also u
__global__ void k_mcor(const double* Z, const double* mobs, const double* mext, float* out){
  __shared__ double mo[DDIM];
  for (int s=threadIdx.x;s<DDIM;s+=256) mo[s]=mobs[s];
  __syncthreads();
  int r=blockIdx.x*256+threadIdx.x;
  if (r>=KDIM) return;
  double acc=0;
  for (int s=0;s<DDIM;s++) acc += Z[(size_t)s*KDIM+r]*mo[s];
  double mc = mext[r]-acc;
  out[r]=(float)mc;
  if (r%5==0) out[OUT_U + r/5]=(float)mc;
}

// l_cor = l_ext - Z^T @ l_obs_ns (64x64 tiles)
__global__ __launch_bounds__(256) void k_lcor(const double* __restrict__ Z, const float* __restrict__ lobs,
                                              const float* __restrict__ lext, float* __restrict__ out){
  __shared__ double As[16][65];
  __shared__ double Bs[16][65];
  int tid=threadIdx.x, tx=tid&15, ty=tid>>4;
  int n0=blockIdx.x*64, m0=blockIdx.y*64;
  double acc[4][4]={};
  for (int k0=0;k0<DDIM;k0+=16){
    for (int e=tid;e<16*64;e+=256){int k=e>>6,mm=e&63; As[k][mm]=Z[(size_t)(k0+k)*KDIM+m0+mm];}
    for (int e=tid;e<16*64;e+=256){int k=e>>6,nn=e&63; Bs[k][nn]=(double)lobs[(size_t)(k0+k)*KDIM+n0+nn];}
    __syncthreads();
    #pragma unroll
    for (int t=0;t<16;t++){
      double av[4],bv[4];
      #pragma unroll
      for (int i=0;i<4;i++){av[i]=As[t][ty+16*i];bv[i]=Bs[t][tx+16*i];}
      #pragma unroll
      for (int i=0;i<4;i++)
        #pragma unroll
        for (int j=0;j<4;j++) acc[i][j]+=av[i]*bv[j];
    }
    __syncthreads();
  }
  #pragma unroll
  for (int i=0;i<4;i++)
    #pragma unroll
    for (int j=0;j<4;j++){
      size_t idx=(size_t)(m0+ty+16*i)*KDIM+n0+tx+16*j;
      out[OUT_LCOR+idx]=(float)((double)lext[idx]-acc[i][j]);
    }
}

extern "C" void kernel_launch(void* const* d_in, const int* in_sizes, int n_in,
                              void* d_out, int out_size, void* d_ws, size_t ws_size,
                              hipStream_t stream) {
  const float* m0  = (const float*)d_in[0];
  const float* l0  = (const float*)d_in[1];
  const float* H   = (const float*)d_in[2];
  const float* bias= (const float*)d_in[3];
  const float* dt  = (const float*)d_in[4];
  const float* a   = (const float*)d_in[5];
  const float* q   = (const float*)d_in[6];
  float* out = (float*)d_out;

  char* w=(char*)d_ws;
  auto alloc=[&](size_t bytes)->char*{ char* p=w; w += ((bytes+255)/256)*256; return p; };
  double* scal  =(double*)alloc(16*8);
  double* mext  =(double*)alloc((size_t)KDIM*8);
  double* mobs  =(double*)alloc((size_t)DDIM*8);
  double* vheadA=(double*)alloc((size_t)QN*8);
  double* Tbuf  =(double*)alloc((size_t)PW*PW*8);
  double* Aq    =(double*)alloc((size_t)QM*QN*8);     // QR working matrix (fp64)
  double* S     =(double*)alloc((size_t)DDIM*DDIM*8); // innovation Gram + chol
  double* G2    =(double*)alloc((size_t)KDIM*KDIM*8); // big Gram -> chol; region reused
  float*  LOBS  =(float*) alloc((size_t)DDIM*KDIM*4);
  float*  X     =(float*) alloc((size_t)KDIM*KDIM*4); // X; later l_ext
  float*  LEXT  = X;
  // after k_extract, G2 region is dead -> reuse:
  double* Linv  = G2;                                  // 512x512
  double* C2    = Linv + (size_t)DDIM*DDIM;            // 512x2560
  double* Y     = C2   + (size_t)DDIM*KDIM;            // 512x2560
  double* Z     = Y    + (size_t)DDIM*KDIM;            // 512x2560

  // ---- extrapolate mean + observe (fused) ----
  k_mext_mobs<<<DDIM,256,0,stream>>>(a, m0, H, bias, dt, mext, mobs);

  // ---- first QR: Householder fp64, LAPACK signs (VtV/T fused in panel) ----
  k_A<<<(QN*QM+255)/256,256,0,stream>>>(H, q, dt, Aq);
  for (int p=0;p<QN/PW;p++){
    int col0=p*PW;
    qr_panel<<<1,1024,0,stream>>>(Aq, vheadA, col0, Tbuf);
    int ntr = QN - col0 - PW;
    if (ntr>0) qr_update<<<ntr,256,0,stream>>>(Aq, vheadA, Tbuf, col0);
  }
  // fused: col norms + triangular solve + diffusion + error
  k_rpost<<<1,512,0,stream>>>(Aq, mobs, scal, out);

  // ---- extrapolated covariance sqrt via Gram + Cholesky ----
  k_X<<<(KDIM*KDIM+255)/256,256,0,stream>>>(a, l0, dt, X);
  syrk_lower<<<dim3(KDIM/64,KDIM/64),256,0,stream>>>(X, q, scal, G2, KDIM);
  chol_diag<<<1,256,0,stream>>>(G2, KDIM, 0);
  for (int k0=0;k0+NB<KDIM;k0+=NB){
    int m = KDIM-k0-NB;
    chol_trsm<<<(m+255)/256,256,0,stream>>>(G2, KDIM, k0);
    chol_syrk_fd<<<dim3(m/64,m/64),256,0,stream>>>(G2, KDIM, k0);
  }
  k_extract<<<(KDIM*KDIM+255)/256,256,0,stream>>>(G2, dt, LEXT);  // G2 dead afterwards

  // ---- correction ----
  gemm64<float,0,float,0,2><<<dim3(KDIM/64,DDIM/64),256,0,stream>>>(H,KDIM, LEXT,KDIM, LOBS,KDIM, KDIM, 1);
  gemm64<float,0,float,1,0><<<dim3(DDIM/64,DDIM/64),256,0,stream>>>(LOBS,KDIM, LOBS,KDIM, S,DDIM, KDIM, 0);
  chol_diag<<<1,256,0,stream>>>(S, DDIM, 0);
  for (int k0=0;k0+NB<DDIM;k0+=NB){
    int m = DDIM-k0-NB;
    chol_trsm<<<(m+255)/256,256,0,stream>>>(S, DDIM, k0);
    chol_syrk_fd<<<dim3(m/64,m/64),256,0,stream>>>(S, DDIM, k0);
  }
  // explicit blocked L^{-1}
  trinv_diag<<<8,256,0,stream>>>(S, Linv);
  for (int d=1;d<8;d++)
    trinv_step<<<8-d,256,0,stream>>>(S, Linv, d);
  // C2 = LOBS @ LEXT^T (crosscov^T), Y = Linv C2, Z = Linv^T Y  (gain = Z^T)
  gemm64<float,0,float,1,0><<<dim3(KDIM/64,DDIM/64),256,0,stream>>>(LOBS,KDIM, LEXT,KDIM, C2,KDIM, KDIM, 2);
  gemm64<double,0,double,0,0><<<dim3(KDIM/64,DDIM/64),256,0,stream>>>(Linv,DDIM, C2,KDIM, Y,KDIM, DDIM, 3);
  gemm64<double,1,double,0,0><<<dim3(KDIM/64,DDIM/64),256,0,stream>>>(Linv,DDIM, Y,KDIM, Z,KDIM, DDIM, 4);

  k_mcor<<<(KDIM+255)/256,256,0,stream>>>(Z, mobs, mext, out);
  k_lcor<<<dim3(KDIM/64,KDIM/64),256,0,stream>>>(Z, LOBS, LEXT, out);
}

// Round 7
// 15545.351 us; speedup vs baseline: 1.7527x; 1.1026x over previous
//
#include <hip/hip_runtime.h>
#include <math.h>

#define KDIM 2560
#define DDIM 512
#define NB 64

#define QM 2560
#define QM2 1024
#define QN 512
#define PW 16
#define UW 4

// out layout (floats): m_cor @0 (2560), l_cor @2560 (2560*2560), u @6556160 (512),
// error @6556672 (512), diffusion @6557184 (1)
#define OUT_LCOR 2560
#define OUT_U    6556160
#define OUT_ERR  6556672
#define OUT_DIFF 6557184

// scal layout (doubles): [0..4]=p_pat, [5..9]=pinv_pat, [10]=diffusion

__global__ void k_setup(const float* dt, double* scal){
  if (threadIdx.x==0 && blockIdx.x==0){
    double adt = fabs((double)dt[0]);
    const double scales[5] = {24.0,6.0,2.0,1.0,1.0};
    for (int i=0;i<5;i++){
      double pw = (double)(4-i)+0.5;
      scal[i]   = pow(adt, pw)/scales[i];
      scal[5+i] = pow(adt,-pw)*scales[i];
    }
  }
}

// fused: mext (block 0 writes) + mobs (one block per row)
__global__ __launch_bounds__(256) void k_mext_mobs(const float* a, const float* m0, const float* H,
                                                   const float* bias, const double* scal,
                                                   double* mext, double* mobs){
  __shared__ double me[KDIM];
  __shared__ double red[256];
  double pp[5], pv[5];
  #pragma unroll
  for (int i=0;i<5;i++){ pp[i]=scal[i]; pv[i]=scal[5+i]; }
  int tid=threadIdx.x;
  for (int r=tid; r<KDIM; r+=256){
    int j=r/5, i=r%5;
    const float* arow = a + (size_t)r*KDIM + 5*j;
    const float* m0b  = m0 + 5*j;
    double acc=0;
    #pragma unroll
    for (int l=0;l<5;l++) acc += (double)arow[l]*pv[l]*(double)m0b[l];
    me[r] = pp[i]*acc;
  }
  __syncthreads();
  if (blockIdx.x==0) for (int r=tid;r<KDIM;r+=256) mext[r]=me[r];
  int b = blockIdx.x;
  const float* Hr = H + (size_t)b*KDIM;
  double acc=0;
  for (int c=tid;c<KDIM;c+=256) acc += (double)Hr[c]*me[c];
  red[tid]=acc; __syncthreads();
  for (int s=128;s>0;s>>=1){ if (tid<s) red[tid]+=red[tid+s]; __syncthreads(); }
  if (tid==0) mobs[b] = red[0] - (double)bias[b];
}

// A = (H @ (p_inv[:,None]*q)).T  split: rows<512 -> Atop (1024-lda col-major),
// rows>=512 -> Abot (2048-lda col-major, for Gram compression)
__global__ void k_A2(const float* H, const float* q, const double* scal,
                     double* Atop, double* Abot){
  int idx = blockIdx.x*blockDim.x+threadIdx.x;
  if (idx >= QN*QM) return;
  double pv[5];
  #pragma unroll
  for (int t=0;t<5;t++) pv[t]=scal[5+t];
  int j = idx / QM;
  int i = idx % QM;
  int bi = i/5;
  double acc=0;
  #pragma unroll
  for (int t=0;t<5;t++)
    acc += (double)H[(size_t)j*QM + 5*bi+t]*pv[t]*(double)q[(size_t)(5*bi+t)*QM + i];
  if (i < 512) Atop[(size_t)j*QM2 + i] = acc;
  else         Abot[(size_t)j*2048 + (i-512)] = acc;
}

// B = chol(Abot^T Abot)^T into AQ rows 512..1023 (upper-triangular)
__global__ void k_copyB(const double* Gbot, double* AQ){
  int idx = blockIdx.x*blockDim.x+threadIdx.x;
  if (idx >= 512*512) return;
  int c = idx/512, rr = idx%512;
  AQ[(size_t)c*QM2 + 512 + rr] = (rr<=c) ? Gbot[(size_t)c*512 + rr] : 0.0;  // B[r][c]=L[c][r]
}

// ---- Householder QR on compressed 1024x512 (LAPACK signs) ----
// register-resident panel: one row per thread (16 dbl/thread), all reductions shuffle/LDS
__global__ __launch_bounds__(1024) void qr_panel(double* A, double* vhead, int col0, double* Tbuf){
  __shared__ double redw[16][PW];
  __shared__ double rednorm[16];
  __shared__ double sh[3];
  __shared__ double wsh[PW];
  __shared__ double alphas[PW], betas[PW];
  __shared__ double VtVs[PW][PW];
  __shared__ double Tsh[PW][PW];
  int tid=threadIdx.x, wid=tid>>6, lane=tid&63;
  int m = QM2 - col0;
  bool on = tid < m;
  double x[PW];
  #pragma unroll
  for (int j=0;j<PW;j++)
    x[j] = on ? A[(size_t)(col0+j)*QM2 + col0 + tid] : 0.0;
  for (int j=0;j<PW;j++){
    double v0 = (tid>=j && on)? x[j] : 0.0;
    double ps = v0*v0;
    #pragma unroll
    for (int o=32;o>0;o>>=1) ps += __shfl_down(ps,o);
    if (lane==0) rednorm[wid]=ps;
    if (tid==j) sh[0]=x[j];
    __syncthreads();
    if (tid==0){
      double s0=0;
      for (int t=0;t<16;t++) s0+=rednorm[t];
      double x1=sh[0];
      double nrm=sqrt(s0);
      double alpha=(x1>=0.0)?-nrm:nrm;     // LAPACK: R_cc = -sign(x1)*||x||
      double v1=x1-alpha;
      double vtv=s0-2.0*alpha*x1+alpha*alpha;
      double b=(vtv>0.0)?2.0/vtv:0.0;
      sh[1]=v1; sh[2]=b;
      alphas[j]=alpha; betas[j]=b;
      vhead[col0+j]=v1;
    }
    __syncthreads();
    if (tid==j) x[j]=sh[1];
    double b=sh[2];
    double v=(tid>=j && on)? x[j] : 0.0;
    // 15 simultaneous dots: t>j -> update dots, t<j -> VtV[t][j]
    #pragma unroll
    for (int t=0;t<PW;t++){
      if (t==j) continue;
      double p=v*x[t];
      #pragma unroll
      for (int o=32;o>0;o>>=1) p+=__shfl_down(p,o);
      if (lane==0) redw[wid][t]=p;
    }
    __syncthreads();
    if (tid<PW && tid!=j){
      double tot=0;
      #pragma unroll
      for (int t2=0;t2<16;t2++) tot+=redw[t2][tid];
      if (tid>j) wsh[tid]=b*tot;
      else       VtVs[tid][j]=tot;
    }
    __syncthreads();
    if (v!=0.0){
      for (int t=j+1;t<PW;t++) x[t]-=wsh[t]*v;
    }
  }
  __syncthreads();
  if (tid<PW){
    int i=tid;
    Tsh[i][i]=betas[i];
    for (int j2=i+1;j2<PW;j2++){
      double z=0;
      for (int t=i;t<j2;t++) z+=Tsh[i][t]*VtVs[t][j2];
      Tsh[i][j2]=-betas[j2]*z;
    }
  }
  __syncthreads();
  for (int e=tid;e<PW*PW;e+=1024){
    int i=e/PW, j2=e%PW;
    Tbuf[e] = (j2>=i)? Tsh[i][j2] : 0.0;
  }
  if (on){
    #pragma unroll
    for (int j=0;j<PW;j++)
      A[(size_t)(col0+j)*QM2 + col0 + tid] = (tid==j)? alphas[j] : x[j];
  }
}

// fused trailing update: a_cc -= V * (T^T (V^T a_cc)); one block per trailing column
__global__ __launch_bounds__(256) void qr_update(double* A, const double* vhead,
                                                 const double* Tbuf, int col0){
  __shared__ double redu[4][PW];
  __shared__ double ysh[PW];
  __shared__ double wsh[PW];
  int tid=threadIdx.x, wid=tid>>6, lane=tid&63;
  int cc=col0+PW+blockIdx.x;
  int m=QM2-col0;
  double a[UW];
  #pragma unroll
  for (int w=0;w<UW;w++){
    int lr=tid+w*256;
    a[w]=(lr<m)? A[(size_t)cc*QM2+col0+lr] : 0.0;
  }
  double acc[PW];
  #pragma unroll
  for (int j=0;j<PW;j++) acc[j]=0;
  #pragma unroll
  for (int w=0;w<UW;w++){
    int lr=tid+w*256;
    if (lr<m){
      #pragma unroll
      for (int j=0;j<PW;j++){
        double vj;
        if (lr>j)       vj=A[(size_t)(col0+j)*QM2+col0+lr];
        else if (lr==j) vj=vhead[col0+j];
        else            vj=0.0;
        acc[j]+=vj*a[w];
      }
    }
  }
  #pragma unroll
  for (int j=0;j<PW;j++){
    double d=acc[j];
    #pragma unroll
    for (int o=32;o>0;o>>=1) d+=__shfl_down(d,o);
    if (lane==0) redu[wid][j]=d;
  }
  __syncthreads();
  if (tid<PW){
    double y=0;
    #pragma unroll
    for (int t=0;t<4;t++) y+=redu[t][tid];
    ysh[tid]=y;
  }
  __syncthreads();
  if (tid<PW){
    double s=0;
    for (int t=0;t<=tid;t++) s+=Tbuf[t*PW+tid]*ysh[t];
    wsh[tid]=s;
  }
  __syncthreads();
  #pragma unroll
  for (int w=0;w<UW;w++){
    int lr=tid+w*256;
    if (lr<m){
      double s=0;
      #pragma unroll
      for (int j=0;j<PW;j++){
        double vj;
        if (lr>j)       vj=A[(size_t)(col0+j)*QM2+col0+lr];
        else if (lr==j) vj=vhead[col0+j];
        else            vj=0.0;
        s+=vj*wsh[j];
      }
      A[(size_t)cc*QM2+col0+lr]=a[w]-s;
    }
  }
}

// fused: R column norms + backward solve R x = m_obs + diffusion + error (R in AQ, lda QM2)
__global__ __launch_bounds__(512) void k_rpost(const double* Aq, const double* mobs,
                                               double* scal, float* out){
  __shared__ double b[DDIM];
  __shared__ double xs[DDIM];
  __shared__ double D[NB][NB+1];
  __shared__ double red[DDIM];
  __shared__ double g1sh[DDIM];
  int tid=threadIdx.x;
  {
    double s=0;
    for (int r=0;r<=tid;r++){ double v=Aq[(size_t)tid*QM2 + r]; s+=v*v; }
    g1sh[tid]=s;
  }
  b[tid]=mobs[tid];
  __syncthreads();
  for (int p=7;p>=0;p--){
    int b0=p*NB;
    for (int e=tid;e<NB*NB;e+=512){ int i=e&63, j2=e>>6; D[i][j2]=Aq[(size_t)(b0+j2)*QM2 + b0+i]; }
    __syncthreads();
    if (tid<64){
      double bi=b[b0+tid];
      for (int k=NB-1;k>=0;k--){
        double bk=__shfl(bi,k);
        double xk=bk/D[k][k];
        if (tid<k) bi-=D[tid][k]*xk;
        if (tid==k) bi=xk;
      }
      xs[b0+tid]=bi;
    }
    __syncthreads();
    if (tid<b0){
      double s=0;
      #pragma unroll 8
      for (int j2=0;j2<NB;j2++) s+=Aq[(size_t)(b0+j2)*QM2 + tid]*xs[b0+j2];
      b[tid]-=s;
    }
    __syncthreads();
  }
  red[tid]=xs[tid]*xs[tid]; __syncthreads();
  for (int s=256;s>0;s>>=1){ if (tid<s) red[tid]+=red[tid+s]; __syncthreads(); }
  double diff=sqrt(red[0]/(double)DDIM);
  if (tid==0){ scal[10]=diff; out[OUT_DIFF]=(float)diff; }
  out[OUT_ERR+tid]=(float)(diff*sqrt(fmax(g1sh[tid],0.0)));
}

// X = a @ (p_inv[:,None]*l0)
__global__ void k_X(const float* a, const float* l0, const double* scal, float* X){
  int idx=blockIdx.x*blockDim.x+threadIdx.x;
  if (idx>=KDIM*KDIM) return;
  double pv[5];
  #pragma unroll
  for (int t=0;t<5;t++) pv[t]=scal[5+t];
  int r=idx/KDIM, c=idx%KDIM;
  int j=r/5;
  const float* arow = a + (size_t)r*KDIM + 5*j;
  double acc=0;
  #pragma unroll
  for (int l=0;l<5;l++)
    acc += (double)arow[l]*pv[l]*(double)l0[(size_t)(5*j+l)*KDIM+c];
  X[idx]=(float)acc;
}

// ---- 64x64-tile GEMM, 4x4 per thread, fp64 accumulate ----
// A: ATR? (K x M row-major) : (M x K). B: BTR? (N x K) : (K x N).
// MODE 0: double C = acc; 1: double C -= acc; 2: float C = acc.
// kmode 0: [0,K); 1: ks=n0; 2: ke=min(K,n0+64); 3: ke=min(K,m0+64); 4: ks=m0
template<typename TA,int ATR,typename TB,int BTR,int MODE>
__global__ __launch_bounds__(256) void gemm64(const TA* __restrict__ A,int lda,
                                              const TB* __restrict__ B,int ldb,
                                              void* __restrict__ Cv,int ldc,
                                              int K,int kmode){
  __shared__ double As[16][65];
  __shared__ double Bs[16][65];
  int tid=threadIdx.x, tx=tid&15, ty=tid>>4;
  int n0=blockIdx.x*64, m0=blockIdx.y*64;
  int ks=0, ke=K;
  if (kmode==1) ks=n0;
  else if (kmode==2) ke=min(K,n0+64);
  else if (kmode==3) ke=min(K,m0+64);
  else if (kmode==4) ks=m0;
  double acc[4][4]={};
  for (int k0=ks;k0<ke;k0+=16){
    if (ATR){
      for (int e=tid;e<16*64;e+=256){int k=e>>6,mm=e&63; As[k][mm]=(double)A[(size_t)(k0+k)*lda+m0+mm];}
    } else {
      for (int e=tid;e<64*16;e+=256){int mm=e>>4,k=e&15; As[k][mm]=(double)A[(size_t)(m0+mm)*lda+k0+k];}
    }
    if (BTR){
      for (int e=tid;e<64*16;e+=256){int nn=e>>4,k=e&15; Bs[k][nn]=(double)B[(size_t)(n0+nn)*ldb+k0+k];}
    } else {
      for (int e=tid;e<16*64;e+=256){int k=e>>6,nn=e&63; Bs[k][nn]=(double)B[(size_t)(k0+k)*ldb+n0+nn];}
    }
    __syncthreads();
    #pragma unroll
    for (int t=0;t<16;t++){
      double av[4],bv[4];
      #pragma unroll
      for (int i=0;i<4;i++){av[i]=As[t][ty+16*i];bv[i]=Bs[t][tx+16*i];}
      #pragma unroll
      for (int i=0;i<4;i++)
        #pragma unroll
        for (int j=0;j<4;j++) acc[i][j]+=av[i]*bv[j];
    }
    __syncthreads();
  }
  #pragma unroll
  for (int i=0;i<4;i++){
    #pragma unroll
    for (int j=0;j<4;j++){
      size_t idx=(size_t)(m0+ty+16*i)*ldc+n0+tx+16*j;
      if (MODE==0) ((double*)Cv)[idx]=acc[i][j];
      else if (MODE==1) ((double*)Cv)[idx]-=acc[i][j];
      else ((float*)Cv)[idx]=(float)acc[i][j];
    }
  }
}

// G (lower tiles) = X X^T (band-limited) + fused diffusion^2 * kron(I, L1 L1^T)
__global__ __launch_bounds__(256) void syrk_lower(const float* __restrict__ X, const float* __restrict__ q,
                                                  const double* __restrict__ scal,
                                                  double* __restrict__ G, int n){
  int S0=blockIdx.x*64, R0=blockIdx.y*64;
  if (S0>R0) return;
  __shared__ double As[16][65];
  __shared__ double Bs[16][65];
  int tid=threadIdx.x, tx=tid&15, ty=tid>>4;
  int kend=min(n, S0+80);
  double acc[4][4]={};
  for (int k0=0;k0<kend;k0+=16){
    for (int e=tid;e<64*16;e+=256){int mm=e>>4,k=e&15; As[k][mm]=(double)X[(size_t)(R0+mm)*n+k0+k];}
    for (int e=tid;e<64*16;e+=256){int nn=e>>4,k=e&15; Bs[k][nn]=(double)X[(size_t)(S0+nn)*n+k0+k];}
    __syncthreads();
    #pragma unroll
    for (int t=0;t<16;t++){
      double av[4],bv[4];
      #pragma unroll
      for (int i=0;i<4;i++){av[i]=As[t][ty+16*i];bv[i]=Bs[t][tx+16*i];}
      #pragma unroll
      for (int i=0;i<4;i++)
        #pragma unroll
        for (int j=0;j<4;j++) acc[i][j]+=av[i]*bv[j];
    }
    __syncthreads();
  }
  double dd = scal[10]*scal[10];
  #pragma unroll
  for (int i=0;i<4;i++)
    #pragma unroll
    for (int j=0;j<4;j++){
      int r=R0+ty+16*i, c=S0+tx+16*j;
      double v=acc[i][j];
      if (c<=r && (r/5)==(c/5)){
        double qq=0;
        #pragma unroll
        for (int k=0;k<5;k++) qq += (double)q[(size_t)(r%5)*KDIM+k]*(double)q[(size_t)(c%5)*KDIM+k];
        v += dd*qq;
      }
      G[(size_t)r*n+c]=v;
    }
}

// ---- blocked Cholesky ----
__global__ __launch_bounds__(256) void chol_diag(double* A, int n, int k0){
  __shared__ double P[NB][NB+1];
  int tid=threadIdx.x;
  for (int e=tid;e<NB*NB;e+=256){int r=e>>6,c=e&63;P[r][c]=A[(size_t)(k0+r)*n+k0+c];}
  int tx=tid&15, ty=tid>>4;
  __syncthreads();
  for (int j=0;j<NB;j++){
    double pj=P[j][j];
    __syncthreads();
    double rpj=1.0/sqrt(fmax(pj,1e-280));
    if (tid>j && tid<NB) P[tid][j]*=rpj;
    if (tid==j) P[j][j]=sqrt(fmax(pj,1e-280));
    __syncthreads();
    #pragma unroll
    for (int a2=0;a2<4;a2++){
      int r=ty+16*a2;
      double lrj=P[r][j];
      #pragma unroll
      for (int b2=0;b2<4;b2++){
        int c=tx+16*b2;
        if (r>j && c>j && c<=r) P[r][c]-=lrj*P[c][j];
      }
    }
    __syncthreads();
  }
  for (int e=tid;e<NB*NB;e+=256){int r=e>>6,c=e&63;A[(size_t)(k0+r)*n+k0+c]=P[r][c];}
}

// rows below panel: Ar = Ar * Lbb^{-T}; LDS-staged coalesced loads, register solve
__global__ __launch_bounds__(256) void chol_trsm(double* A,int n,int k0){
  __shared__ double Ls[NB][NB+1];
  __shared__ double St[NB][NB+1];
  __shared__ double rec[NB];
  int tid=threadIdx.x;
  for (int e=tid;e<NB*NB;e+=256){int r=e>>6,c=e&63;Ls[r][c]=A[(size_t)(k0+r)*n+k0+c];}
  __syncthreads();
  if (tid<NB) rec[tid]=1.0/Ls[tid][tid];
  int base=k0+NB+blockIdx.x*256;
  int myrow=base+tid;
  int mychunk=tid>>6, lrow=tid&63;
  double ar[NB];
  for (int ch=0;ch<4;ch++){
    int r0=base+ch*64;
    for (int e=tid;e<NB*NB;e+=256){
      int r=e>>6,c=e&63;
      if (r0+r<n) St[r][c]=A[(size_t)(r0+r)*n+k0+c];
    }
    __syncthreads();
    if (mychunk==ch && myrow<n){
      #pragma unroll
      for (int c=0;c<NB;c++) ar[c]=St[lrow][c];
    }
    __syncthreads();
  }
  if (myrow<n){
    #pragma unroll
    for (int j=0;j<NB;j++){
      double s=ar[j];
      #pragma unroll
      for (int t=0;t<j;t++) s-=ar[t]*Ls[j][t];
      ar[j]=s*rec[j];
    }
  }
  for (int ch=0;ch<4;ch++){
    int r0=base+ch*64;
    if (mychunk==ch && myrow<n){
      #pragma unroll
      for (int c=0;c<NB;c++) St[lrow][c]=ar[c];
    }
    __syncthreads();
    for (int e=tid;e<NB*NB;e+=256){
      int r=e>>6,c=e&63;
      if (r0+r<n) A[(size_t)(r0+r)*n+k0+c]=St[r][c];
    }
    __syncthreads();
  }
}

// trailing syrk (64x64 tiles, skip upper) with fused factorization of next diag block
__global__ __launch_bounds__(256) void chol_syrk_fd(double* A,int n,int k0){
  int ts0=k0+NB;
  int S0=ts0+blockIdx.x*64, R0=ts0+blockIdx.y*64;
  if (S0>R0) return;
  __shared__ double As[16][65];
  __shared__ double Bs[16][65];
  __shared__ double P[NB][NB+1];
  int tid=threadIdx.x, tx=tid&15, ty=tid>>4;
  double acc[4][4]={};
  for (int k0i=0;k0i<NB;k0i+=16){
    for (int e=tid;e<64*16;e+=256){int mm=e>>4,k=e&15; As[k][mm]=A[(size_t)(R0+mm)*n+k0+k0i+k];}
    for (int e=tid;e<64*16;e+=256){int nn=e>>4,k=e&15; Bs[k][nn]=A[(size_t)(S0+nn)*n+k0+k0i+k];}
    __syncthreads();
    #pragma unroll
    for (int t=0;t<16;t++){
      double av[4],bv[4];
      #pragma unroll
      for (int i=0;i<4;i++){av[i]=As[t][ty+16*i];bv[i]=Bs[t][tx+16*i];}
      #pragma unroll
      for (int i=0;i<4;i++)
        #pragma unroll
        for (int j=0;j<4;j++) acc[i][j]+=av[i]*bv[j];
    }
    __syncthreads();
  }
  if (!(blockIdx.x==0 && blockIdx.y==0)){
    #pragma unroll
    for (int i=0;i<4;i++)
      #pragma unroll
      for (int j=0;j<4;j++)
        A[(size_t)(R0+ty+16*i)*n+S0+tx+16*j]-=acc[i][j];
    return;
  }
  #pragma unroll
  for (int i=0;i<4;i++)
    #pragma unroll
    for (int j=0;j<4;j++)
      P[ty+16*i][tx+16*j] = A[(size_t)(R0+ty+16*i)*n+S0+tx+16*j] - acc[i][j];
  __syncthreads();
  for (int j=0;j<NB;j++){
    double pj=P[j][j];
    __syncthreads();
    double rpj=1.0/sqrt(fmax(pj,1e-280));
    if (tid>j && tid<NB) P[tid][j]*=rpj;
    if (tid==j) P[j][j]=sqrt(fmax(pj,1e-280));
    __syncthreads();
    #pragma unroll
    for (int a2=0;a2<4;a2++){
      int r=ty+16*a2;
      double lrj=P[r][j];
      #pragma unroll
      for (int b2=0;b2<4;b2++){
        int c=tx+16*b2;
        if (r>j && c>j && c<=r) P[r][c]-=lrj*P[c][j];
      }
    }
    __syncthreads();
  }
  for (int e=tid;e<NB*NB;e+=256){int r=e>>6,c=e&63;A[(size_t)(ts0+r)*n+ts0+c]=P[r][c];}
}

// l_ext (f32) = p[:,None] * chol(G2), zero strict upper
__global__ void k_extract(const double* G2, const double* scal, float* lext){
  int idx=blockIdx.x*blockDim.x+threadIdx.x;
  if (idx>=KDIM*KDIM) return;
  int r=idx/KDIM, c=idx%KDIM;
  double v = (c<=r)? scal[r%5]*G2[idx] : 0.0;
  lext[idx]=(float)v;
}

// ---- explicit blocked inverse of lower-triangular L (512) ----
__global__ __launch_bounds__(256) void trinv_diag(const double* S, double* Linv){
  __shared__ double Ls[NB][NB+1];
  __shared__ double Ti[NB][NB+1];
  int jb=blockIdx.x, tid=threadIdx.x;
  for (int e=tid; e<DDIM*NB; e+=256){
    int r=e/NB, c=e%NB;
    Linv[(size_t)r*DDIM + jb*NB + c]=0.0;
  }
  for (int e=tid;e<NB*NB;e+=256){int r=e>>6,c=e&63; Ls[r][c]=S[(size_t)(jb*NB+r)*DDIM + jb*NB+c];}
  __syncthreads();
  if (tid<NB){
    int c=tid;
    for (int r=c;r<NB;r++){
      double s=(r==c)?1.0:0.0;
      for (int t=c;t<r;t++) s-=Ls[r][t]*Ti[t][c];
      Ti[r][c]=s/Ls[r][r];
    }
    for (int r=0;r<c;r++) Ti[r][c]=0.0;
  }
  __syncthreads();
  for (int e=tid;e<NB*NB;e+=256){int r=e>>6,c=e&63; Linv[(size_t)(jb*NB+r)*DDIM + jb*NB+c]=Ti[r][c];}
}

__global__ __launch_bounds__(256) void trinv_step(const double* S, double* Linv, int d){
  __shared__ double As[16][65];
  __shared__ double Bs[16][65];
  __shared__ double Ps[NB][NB+1];
  int jb=blockIdx.x, ib=jb+d;
  int tid=threadIdx.x, tx=tid&15, ty=tid>>4;
  double acc[4][4]={};
  int kstart=jb*NB, kend=ib*NB;
  for (int k0=kstart;k0<kend;k0+=16){
    for (int e=tid;e<64*16;e+=256){int mm=e>>4,k=e&15; As[k][mm]=S[(size_t)(ib*NB+mm)*DDIM + k0+k];}
    for (int e=tid;e<16*64;e+=256){int k=e>>6,nn=e&63; Bs[k][nn]=Linv[(size_t)(k0+k)*DDIM + jb*NB+nn];}
    __syncthreads();
    #pragma unroll
    for (int t=0;t<16;t++){
      double av[4],bv[4];
      #pragma unroll
      for (int i=0;i<4;i++){av[i]=As[t][ty+16*i];bv[i]=Bs[t][tx+16*i];}
      #pragma unroll
      for (int i=0;i<4;i++)
        #pragma unroll
        for (int j=0;j<4;j++) acc[i][j]+=av[i]*bv[j];
    }
    __syncthreads();
  }
  #pragma unroll
  for (int i=0;i<4;i++)
    #pragma unroll
    for (int j=0;j<4;j++) Ps[ty+16*i][tx+16*j]=acc[i][j];
  double o[4][4]={};
  __syncthreads();
  for (int k0=0;k0<NB;k0+=16){
    for (int e=tid;e<64*16;e+=256){int mm=e>>4,k=e&15; As[k][mm]=Linv[(size_t)(ib*NB+mm)*DDIM + ib*NB+k0+k];}
    __syncthreads();
    #pragma unroll
    for (int t=0;t<16;t++){
      double av[4],bv[4];
      #pragma unroll
      for (int i=0;i<4;i++){av[i]=As[t][ty+16*i];bv[i]=Ps[k0+t][tx+16*i];}
      #pragma unroll
      for (int i=0;i<4;i++)
        #pragma unroll
        for (int j=0;j<4;j++) o[i][j]+=av[i]*bv[j];
    }
    __syncthreads();
  }
  #pragma unroll
  for (int i=0;i<4;i++)
    #pragma unroll
    for (int j=0;j<4;j++)
      Linv[(size_t)(ib*NB+ty+16*i)*DDIM + jb*NB+tx+16*j] = -o[i][j];
}

// m_cor = m_ext - Z^T @ m_obs; also u
__global__ void k_mcor(const double* Z, const double* mobs, const double* mext, float* out){
  __shared__ double mo[DDIM];
  for (int s=threadIdx.x;s<DDIM;s+=256) mo[s]=mobs[s];
  __syncthreads();
  int r=blockIdx.x*256+threadIdx.x;
  if (r>=KDIM) return;
  double acc=0;
  for (int s=0;s<DDIM;s++) acc += Z[(size_t)s*KDIM+r]*mo[s];
  double mc = mext[r]-acc;
  out[r]=(float)mc;
  if (r%5==0) out[OUT_U + r/5]=(float)mc;
}

// l_cor = l_ext - Z^T @ l_obs_ns (64x64 tiles)
__global__ __launch_bounds__(256) void k_lcor(const double* __restrict__ Z, const float* __restrict__ lobs,
                                              const float* __restrict__ lext, float* __restrict__ out){
  __shared__ double As[16][65];
  __shared__ double Bs[16][65];
  int tid=threadIdx.x, tx=tid&15, ty=tid>>4;
  int n0=blockIdx.x*64, m0=blockIdx.y*64;
  double acc[4][4]={};
  for (int k0=0;k0<DDIM;k0+=16){
    for (int e=tid;e<16*64;e+=256){int k=e>>6,mm=e&63; As[k][mm]=Z[(size_t)(k0+k)*KDIM+m0+mm];}
    for (int e=tid;e<16*64;e+=256){int k=e>>6,nn=e&63; Bs[k][nn]=(double)lobs[(size_t)(k0+k)*KDIM+n0+nn];}
    __syncthreads();
    #pragma unroll
    for (int t=0;t<16;t++){
      double av[4],bv[4];
      #pragma unroll
      for (int i=0;i<4;i++){av[i]=As[t][ty+16*i];bv[i]=Bs[t][tx+16*i];}
      #pragma unroll
      for (int i=0;i<4;i++)
        #pragma unroll
        for (int j=0;j<4;j++) acc[i][j]+=av[i]*bv[j];
    }
    __syncthreads();
  }
  #pragma unroll
  for (int i=0;i<4;i++)
    #pragma unroll
    for (int j=0;j<4;j++){
      size_t idx=(size_t)(m0+ty+16*i)*KDIM+n0+tx+16*j;
      out[OUT_LCOR+idx]=(float)((double)lext[idx]-acc[i][j]);
    }
}

extern "C" void kernel_launch(void* const* d_in, const int* in_sizes, int n_in,
                              void* d_out, int out_size, void* d_ws, size_t ws_size,
                              hipStream_t stream) {
  const float* m0  = (const float*)d_in[0];
  const float* l0  = (const float*)d_in[1];
  const float* H   = (const float*)d_in[2];
  const float* bias= (const float*)d_in[3];
  const float* dt  = (const float*)d_in[4];
  const float* a   = (const float*)d_in[5];
  const float* q   = (const float*)d_in[6];
  float* out = (float*)d_out;

  char* w=(char*)d_ws;
  auto alloc=[&](size_t bytes)->char*{ char* p=w; w += ((bytes+255)/256)*256; return p; };
  double* scal  =(double*)alloc(16*8);
  double* mext  =(double*)alloc((size_t)KDIM*8);
  double* mobs  =(double*)alloc((size_t)DDIM*8);
  double* vheadA=(double*)alloc((size_t)QN*8);
  double* Tbuf  =(double*)alloc((size_t)PW*PW*8);
  double* AQ    =(double*)alloc((size_t)QM2*QN*8);    // compressed QR matrix (1024x512 col-major)
  double* S     =(double*)alloc((size_t)DDIM*DDIM*8); // innovation Gram + chol
  double* G2    =(double*)alloc((size_t)KDIM*KDIM*8); // big Gram -> chol; region reused
  float*  LOBS  =(float*) alloc((size_t)DDIM*KDIM*4);
  float*  X     =(float*) alloc((size_t)KDIM*KDIM*4); // X; later l_ext
  float*  LEXT  = X;
  // G2 region used as scratch BEFORE syrk_lower (QR compression):
  double* Abot  = G2;                                  // 2048x512 col-major
  double* Gbot  = Abot + (size_t)2048*512;             // 512x512
  // after k_extract, G2 region reused again:
  double* Linv  = G2;                                  // 512x512
  double* C2    = Linv + (size_t)DDIM*DDIM;            // 512x2560
  double* Y     = C2   + (size_t)DDIM*KDIM;            // 512x2560
  double* Z     = Y    + (size_t)DDIM*KDIM;            // 512x2560

  // ---- setup + extrapolate mean + observe ----
  k_setup<<<1,1,0,stream>>>(dt, scal);
  k_mext_mobs<<<DDIM,256,0,stream>>>(a, m0, H, bias, scal, mext, mobs);

  // ---- first QR, compressed: A'' = [A_top(512); chol(A_bot^T A_bot)^T] (R identical, signs incl.)
  k_A2<<<(QN*QM+255)/256,256,0,stream>>>(H, q, scal, AQ, Abot);
  gemm64<double,0,double,1,0><<<dim3(8,8),256,0,stream>>>(Abot,2048, Abot,2048, Gbot,512, 2048, 0);
  chol_diag<<<1,256,0,stream>>>(Gbot,512,0);
  for (int k0=0;k0+NB<512;k0+=NB){
    int m = 512-k0-NB;
    chol_trsm<<<(m+255)/256,256,0,stream>>>(Gbot,512,k0);
    chol_syrk_fd<<<dim3(m/64,m/64),256,0,stream>>>(Gbot,512,k0);
  }
  k_copyB<<<(512*512+255)/256,256,0,stream>>>(Gbot, AQ);
  for (int p=0;p<QN/PW;p++){
    int col0=p*PW;
    qr_panel<<<1,1024,0,stream>>>(AQ, vheadA, col0, Tbuf);
    int ntr = QN - col0 - PW;
    if (ntr>0) qr_update<<<ntr,256,0,stream>>>(AQ, vheadA, Tbuf, col0);
  }
  k_rpost<<<1,512,0,stream>>>(AQ, mobs, scal, out);

  // ---- extrapolated covariance sqrt via Gram + Cholesky ----
  k_X<<<(KDIM*KDIM+255)/256,256,0,stream>>>(a, l0, scal, X);
  syrk_lower<<<dim3(KDIM/64,KDIM/64),256,0,stream>>>(X, q, scal, G2, KDIM);
  chol_diag<<<1,256,0,stream>>>(G2, KDIM, 0);
  for (int k0=0;k0+NB<KDIM;k0+=NB){
    int m = KDIM-k0-NB;
    chol_trsm<<<(m+255)/256,256,0,stream>>>(G2, KDIM, k0);
    chol_syrk_fd<<<dim3(m/64,m/64),256,0,stream>>>(G2, KDIM, k0);
  }
  k_extract<<<(KDIM*KDIM+255)/256,256,0,stream>>>(G2, scal, LEXT);  // G2 dead afterwards

  // ---- correction ----
  gemm64<float,0,float,0,2><<<dim3(KDIM/64,DDIM/64),256,0,stream>>>(H,KDIM, LEXT,KDIM, LOBS,KDIM, KDIM, 1);
  gemm64<float,0,float,1,0><<<dim3(DDIM/64,DDIM/64),256,0,stream>>>(LOBS,KDIM, LOBS,KDIM, S,DDIM, KDIM, 0);
  chol_diag<<<1,256,0,stream>>>(S, DDIM, 0);
  for (int k0=0;k0+NB<DDIM;k0+=NB){
    int m = DDIM-k0-NB;
    chol_trsm<<<(m+255)/256,256,0,stream>>>(S, DDIM, k0);
    chol_syrk_fd<<<dim3(m/64,m/64),256,0,stream>>>(S, DDIM, k0);
  }
  trinv_diag<<<8,256,0,stream>>>(S, Linv);
  for (int d=1;d<8;d++)
    trinv_step<<<8-d,256,0,stream>>>(S, Linv, d);
  gemm64<float,0,float,1,0><<<dim3(KDIM/64,DDIM/64),256,0,stream>>>(LOBS,KDIM, LEXT,KDIM, C2,KDIM, KDIM, 2);
  gemm64<double,0,double,0,0><<<dim3(KDIM/64,DDIM/64),256,0,stream>>>(Linv,DDIM, C2,KDIM, Y,KDIM, DDIM, 3);
  gemm64<double,1,double,0,0><<<dim3(KDIM/64,DDIM/64),256,0,stream>>>(Linv,DDIM, Y,KDIM, Z,KDIM, DDIM, 4);

  k_mcor<<<(KDIM+255)/256,256,0,stream>>>(Z, mobs, mext, out);
  k_lcor<<<dim3(KDIM/64,KDIM/64),256,0,stream>>>(Z, LOBS, LEXT, out);
}